// Round 4
// baseline (1597.345 us; speedup 1.0000x reference)
//
#include <hip/hip_runtime.h>

typedef __bf16 bf16_t;
typedef __bf16 bf16x8 __attribute__((ext_vector_type(8)));
typedef float f32x4 __attribute__((ext_vector_type(4)));
typedef unsigned short u16;

#define DEV static __device__ __forceinline__

DEV float bf2f(u16 u) { __bf16 h = __builtin_bit_cast(__bf16, u); return (float)h; }
DEV u16 f2bf(float f) { __bf16 h = (__bf16)f; return __builtin_bit_cast(u16, h); }

// async global->LDS, 16B per lane; lds base must be wave-uniform.
DEV void gll16(bf16_t* lds, const bf16_t* g) {
    __builtin_amdgcn_global_load_lds(
        (const __attribute__((address_space(1))) void*)g,
        (__attribute__((address_space(3))) void*)lds, 16, 0, 0);
}

// ---------------------------------------------------------------------------
// 256x256-tile GEMM, 512 threads (8 waves, 2Mx4N), BK=32, double-buffered LDS
// (64 KiB), raw s_barrier + counted hand-placed vmcnt (no compiler drain),
// setprio around MFMA clusters, XCD-swizzled block id.
// Per wave: 128x64 output = 8x4 frags; per K-tile: 2 phases x 16 MFMA.
// EPI: 0 = bf16 out (+f32 bias), 1 = bf16 out + bias + relu
// ---------------------------------------------------------------------------
template <int EPI>
__global__ __launch_bounds__(512, 1)
void gemm_bt8(const bf16_t* __restrict__ A, int lda,
              const bf16_t* __restrict__ Bt, int ldb,
              bf16_t* __restrict__ C, int ldc,
              const float* __restrict__ bias, int K)
{
    __shared__ bf16_t Al[2][256 * 32];
    __shared__ bf16_t Bl[2][256 * 32];
    const int tid = threadIdx.x, w = tid >> 6, l = tid & 63;

    // XCD-aware bijective swizzle (nlin % 8 == 0 for all our grids)
    const int gx = gridDim.x;
    int lin = blockIdx.y * gx + blockIdx.x;
    const int nlin = gx * gridDim.y;
    lin = (lin & 7) * (nlin >> 3) + (lin >> 3);
    const size_t row0 = (size_t)(lin / gx) * 256;
    const size_t col0 = (size_t)(lin % gx) * 256;

    const int wr = w >> 2, wc = w & 3;
    const int wm = wr * 128, wn = wc * 64;

    // staging: issue j covers rows j*128..; this wave stages rows w*16+(l>>2)
    const int srow = w * 16 + (l >> 2);
    const int scol = (l & 3) * 8;
    const bf16_t* Ag = A  + (row0 + srow) * (size_t)lda + scol;
    const bf16_t* Bg = Bt + (col0 + srow) * (size_t)ldb + scol;

    f32x4 acc[8][4] = {};
    const int NT = K >> 5;

    // prologue: stage tile 0, full drain
    gll16(&Al[0][w * 512],        Ag);
    gll16(&Al[0][4096 + w * 512], Ag + (size_t)128 * lda);
    gll16(&Bl[0][w * 512],        Bg);
    gll16(&Bl[0][4096 + w * 512], Bg + (size_t)128 * ldb);
    asm volatile("s_waitcnt vmcnt(0)" ::: "memory");
    __builtin_amdgcn_s_barrier();

    const int fr = l & 15, k8 = (l >> 4) * 8;
    for (int t = 0; t < NT; ++t) {
        const int cur = t & 1, nxt = cur ^ 1;
        const int k0n = (t + 1) << 5;
        // ---- phase A: read B(all) + A(mi 0..3); prefetch next A ----
        bf16x8 bfr[4], afr[4];
#pragma unroll
        for (int ni = 0; ni < 4; ni++)
            bfr[ni] = *(const bf16x8*)&Bl[cur][(wn + ni * 16 + fr) * 32 + k8];
#pragma unroll
        for (int mi = 0; mi < 4; mi++)
            afr[mi] = *(const bf16x8*)&Al[cur][(wm + mi * 16 + fr) * 32 + k8];
        if (t + 1 < NT) {
            gll16(&Al[nxt][w * 512],        Ag + k0n);
            gll16(&Al[nxt][4096 + w * 512], Ag + (size_t)128 * lda + k0n);
        }
        __builtin_amdgcn_s_barrier();
        __builtin_amdgcn_s_setprio(1);
#pragma unroll
        for (int mi = 0; mi < 4; mi++)
#pragma unroll
            for (int ni = 0; ni < 4; ni++)
                acc[mi][ni] = __builtin_amdgcn_mfma_f32_16x16x32_bf16(afr[mi], bfr[ni], acc[mi][ni], 0, 0, 0);
        __builtin_amdgcn_s_setprio(0);
        __builtin_amdgcn_s_barrier();
        // ---- phase B: read A(mi 4..7); prefetch next B ----
        bf16x8 af2[4];
#pragma unroll
        for (int mi = 0; mi < 4; mi++)
            af2[mi] = *(const bf16x8*)&Al[cur][(wm + 64 + mi * 16 + fr) * 32 + k8];
        if (t + 1 < NT) {
            gll16(&Bl[nxt][w * 512],        Bg + k0n);
            gll16(&Bl[nxt][4096 + w * 512], Bg + (size_t)128 * ldb + k0n);
        }
        __builtin_amdgcn_s_barrier();
        __builtin_amdgcn_s_setprio(1);
#pragma unroll
        for (int mi = 0; mi < 4; mi++)
#pragma unroll
            for (int ni = 0; ni < 4; ni++)
                acc[4 + mi][ni] = __builtin_amdgcn_mfma_f32_16x16x32_bf16(af2[mi], bfr[ni], acc[4 + mi][ni], 0, 0, 0);
        __builtin_amdgcn_s_setprio(0);
        // drain next tile's loads (the only vmem wait in the loop), then sync
        asm volatile("s_waitcnt vmcnt(0)" ::: "memory");
        __builtin_amdgcn_s_barrier();
    }

    const int cr = (l >> 4) * 4, cc = l & 15;
#pragma unroll
    for (int ni = 0; ni < 4; ni++) {
        size_t c = col0 + wn + ni * 16 + cc;
        float bv = bias ? bias[c] : 0.f;
#pragma unroll
        for (int mi = 0; mi < 8; mi++) {
            size_t r = row0 + wm + mi * 16 + cr;
#pragma unroll
            for (int j = 0; j < 4; j++) {
                float v = acc[mi][ni][j] + bv;
                if (EPI == 1) v = fmaxf(v, 0.f);
                C[(r + j) * ldc + c] = (bf16_t)v;
            }
        }
    }
}

// ---------------------------------------------------------------------------
// GEMM: C[M,N] = A[M,K] * Bt[N,K]^T (+bias), 128x128 tile, BK=64, 4 waves.
// XOR-swizzled LDS (conflict-free), XCD-swizzled block id.
// EPI: 0 = bf16 out (+f32 bias), 1 = + relu, 2 = f32 out * scale
// ---------------------------------------------------------------------------
template <int EPI>
__global__ __launch_bounds__(256)
void gemm_bt(const bf16_t* __restrict__ A, int lda, long sA,
             const bf16_t* __restrict__ Bt, int ldb, long sB,
             void* __restrict__ Cv, int ldc, long sC,
             const float* __restrict__ bias, int K, float scale)
{
    __shared__ bf16_t Alds[128 * 64];
    __shared__ bf16_t Blds[128 * 64];
    const int tid = threadIdx.x, w = tid >> 6, l = tid & 63;
    const int bz = blockIdx.z;

    const int gx = gridDim.x;
    int lin = blockIdx.y * gx + blockIdx.x;
    const int nlin = gx * gridDim.y;
    lin = (lin & 7) * (nlin >> 3) + (lin >> 3);
    const size_t row0 = (size_t)(lin / gx) * 128;
    const size_t col0 = (size_t)(lin % gx) * 128;

    A  += (size_t)bz * sA;
    Bt += (size_t)bz * sB;

    const int lr = l >> 3;            // row within an 8-row chunk
    const int sl = (l & 7) ^ lr;      // pre-swizzled source 16B-slot
    const bf16_t* Ag = A  + (row0 + (size_t)(w * 32) + lr) * lda + sl * 8;
    const bf16_t* Bg = Bt + (col0 + (size_t)(w * 32) + lr) * ldb + sl * 8;
    bf16_t* Al = &Alds[(w * 32) * 64];
    bf16_t* Bl = &Blds[(w * 32) * 64];

    const int wm = (w >> 1) * 64, wn = (w & 1) * 64;
    f32x4 acc[4][4] = {};

    for (int k0 = 0; k0 < K; k0 += 64) {
#pragma unroll
        for (int c = 0; c < 4; c++) {
            gll16(Al + c * 8 * 64, Ag + (size_t)(c * 8) * lda + k0);
            gll16(Bl + c * 8 * 64, Bg + (size_t)(c * 8) * ldb + k0);
        }
        __syncthreads();

#pragma unroll
        for (int ks = 0; ks < 2; ks++) {
            bf16x8 afr[4], bfr[4];
#pragma unroll
            for (int i = 0; i < 4; i++) {
                const int fr = i * 16 + (l & 15);
                const int slot = (ks * 4 + (l >> 4)) ^ (l & 7);
                afr[i] = *(const bf16x8*)&Alds[(wm + fr) * 64 + slot * 8];
                bfr[i] = *(const bf16x8*)&Blds[(wn + fr) * 64 + slot * 8];
            }
#pragma unroll
            for (int mi = 0; mi < 4; mi++)
#pragma unroll
                for (int ni = 0; ni < 4; ni++)
                    acc[mi][ni] = __builtin_amdgcn_mfma_f32_16x16x32_bf16(afr[mi], bfr[ni], acc[mi][ni], 0, 0, 0);
        }
        __syncthreads();
    }

    const int cr = (l >> 4) * 4, cc = l & 15;
    if (EPI == 2) {
        float* C = (float*)Cv + (size_t)bz * sC;
#pragma unroll
        for (int mi = 0; mi < 4; mi++)
#pragma unroll
            for (int ni = 0; ni < 4; ni++) {
                size_t r = row0 + wm + mi * 16 + cr;
                size_t c = col0 + wn + ni * 16 + cc;
#pragma unroll
                for (int j = 0; j < 4; j++)
                    C[(r + j) * ldc + c] = acc[mi][ni][j] * scale;
            }
    } else {
        bf16_t* C = (bf16_t*)Cv + (size_t)bz * sC;
#pragma unroll
        for (int ni = 0; ni < 4; ni++) {
            size_t c = col0 + wn + ni * 16 + cc;
            float bv = bias ? bias[c] : 0.f;
#pragma unroll
            for (int mi = 0; mi < 4; mi++) {
                size_t r = row0 + wm + mi * 16 + cr;
#pragma unroll
                for (int j = 0; j < 4; j++) {
                    float v = acc[mi][ni][j] + bv;
                    if (EPI == 1) v = fmaxf(v, 0.f);
                    C[(r + j) * ldc + c] = (bf16_t)v;
                }
            }
        }
    }
}

// ---------------------------------------------------------------------------
// convert-transpose: f32 in [R][C] -> bf16 out [C][R]. grid=(C/64, R/64).
// ---------------------------------------------------------------------------
__global__ __launch_bounds__(256)
void transpose_f32_bf16(const float* __restrict__ in, bf16_t* __restrict__ out,
                        int ldin, int ldout)
{
    __shared__ bf16_t t[64][72];
    const int bx = blockIdx.x * 64;  // input col base
    const int by = blockIdx.y * 64;  // input row base
    const int tid = threadIdx.x;
    const int cj = (tid & 15) * 4, ri = tid >> 4;
#pragma unroll
    for (int k = 0; k < 4; k++) {
        int r = ri + k * 16;
        float4 v = *(const float4*)&in[(size_t)(by + r) * ldin + bx + cj];
        ushort4 o = {f2bf(v.x), f2bf(v.y), f2bf(v.z), f2bf(v.w)};
        *(ushort4*)&t[r][cj] = o;
    }
    __syncthreads();
#pragma unroll
    for (int k = 0; k < 4; k++) {
        int i = ri + k * 16;
        ushort4 o;
        o.x = __builtin_bit_cast(u16, t[cj + 0][i]);
        o.y = __builtin_bit_cast(u16, t[cj + 1][i]);
        o.z = __builtin_bit_cast(u16, t[cj + 2][i]);
        o.w = __builtin_bit_cast(u16, t[cj + 3][i]);
        *(ushort4*)&out[(size_t)(bx + i) * ldout + by + cj] = o;
    }
}

// bf16 transpose (for V): in [R][C] (ld ldin) -> out [C][R] (ld ldout)
__global__ __launch_bounds__(256)
void transpose_bf16(const bf16_t* __restrict__ in, bf16_t* __restrict__ out,
                    int ldin, int ldout, long sin_, long sout_)
{
    __shared__ bf16_t t[64][72];
    in  += (size_t)blockIdx.z * sin_;
    out += (size_t)blockIdx.z * sout_;
    const int bx = blockIdx.x * 64;
    const int by = blockIdx.y * 64;
    const int tid = threadIdx.x;
    const int cj = (tid & 15) * 4, ri = tid >> 4;
#pragma unroll
    for (int k = 0; k < 4; k++) {
        int r = ri + k * 16;
        *(ushort4*)&t[r][cj] = *(const ushort4*)&in[(size_t)(by + r) * ldin + bx + cj];
    }
    __syncthreads();
#pragma unroll
    for (int k = 0; k < 4; k++) {
        int i = ri + k * 16;
        ushort4 o;
        o.x = __builtin_bit_cast(u16, t[cj + 0][i]);
        o.y = __builtin_bit_cast(u16, t[cj + 1][i]);
        o.z = __builtin_bit_cast(u16, t[cj + 2][i]);
        o.w = __builtin_bit_cast(u16, t[cj + 3][i]);
        *(ushort4*)&out[(size_t)(bx + i) * ldout + by + cj] = o;
    }
}

// ---------------------------------------------------------------------------
// embedding (f32 table) + sinusoidal PE -> x (f32) and xb (bf16). grid = 4096.
// ---------------------------------------------------------------------------
__global__ __launch_bounds__(256)
void embed_kernel(const int* __restrict__ ids, const float* __restrict__ emb,
                  float* __restrict__ x, bf16_t* __restrict__ xb)
{
    const int row = blockIdx.x;
    const int s = row & 1023;
    const int id = ids[row];
    const float* er = emb + (size_t)id * 1024;
    float* xr = x + (size_t)row * 1024;
    bf16_t* br = xb + (size_t)row * 1024;
#pragma unroll
    for (int k = 0; k < 2; k++) {
        int i = threadIdx.x + 256 * k;  // pair index 0..511
        int d = 2 * i;
        float dv = expf((float)d * -0.008994473019508f);  // -ln(10000)/1024
        float ph = (float)s * dv;
        float sv, cv;
        sincosf(ph, &sv, &cv);
        float2 ev = *(const float2*)&er[d];
        float x0 = ev.x + sv;
        float x1 = ev.y + cv;
        float2 xo = {x0, x1};
        *(float2*)&xr[d] = xo;
        ushort2 bo = {f2bf(x0), f2bf(x1)};
        *(ushort2*)&br[d] = bo;
    }
}

// ---------------------------------------------------------------------------
// masked softmax over rows of f32 scores -> bf16 probs. One wave per row.
// ---------------------------------------------------------------------------
__global__ __launch_bounds__(256)
void softmax_kernel(const float* __restrict__ sc, const int* __restrict__ amask,
                    bf16_t* __restrict__ p)
{
    const int row = blockIdx.x * 4 + (threadIdx.x >> 6);
    const int l = threadIdx.x & 63;
    const int b = row >> 10;
    const float* s = sc + (size_t)row * 1024;
    const int* m = amask + (size_t)b * 1024;
    float v[16];
    float mx = -3.0e38f;
#pragma unroll
    for (int i = 0; i < 4; i++) {
        int c = 4 * l + 256 * i;
        float4 sv = *(const float4*)&s[c];
        int4 mv = *(const int4*)&m[c];
        v[4 * i + 0] = mv.x ? sv.x : -1e9f;
        v[4 * i + 1] = mv.y ? sv.y : -1e9f;
        v[4 * i + 2] = mv.z ? sv.z : -1e9f;
        v[4 * i + 3] = mv.w ? sv.w : -1e9f;
        mx = fmaxf(mx, fmaxf(fmaxf(v[4 * i], v[4 * i + 1]), fmaxf(v[4 * i + 2], v[4 * i + 3])));
    }
#pragma unroll
    for (int o = 32; o; o >>= 1) mx = fmaxf(mx, __shfl_xor(mx, o, 64));
    float sum = 0.f;
#pragma unroll
    for (int i = 0; i < 16; i++) { v[i] = __expf(v[i] - mx); sum += v[i]; }
#pragma unroll
    for (int o = 32; o; o >>= 1) sum += __shfl_xor(sum, o, 64);
    float inv = 1.0f / sum;
#pragma unroll
    for (int i = 0; i < 4; i++) {
        int c = 4 * l + 256 * i;
        ushort4 st;
        st.x = f2bf(v[4 * i + 0] * inv);
        st.y = f2bf(v[4 * i + 1] * inv);
        st.z = f2bf(v[4 * i + 2] * inv);
        st.w = f2bf(v[4 * i + 3] * inv);
        *(ushort4*)&p[(size_t)row * 1024 + c] = st;
    }
}

// ---------------------------------------------------------------------------
// residual + LayerNorm: t = xin + add; y = LN(t)*g + beta (g,beta f32)
// writes y to xout (f32) and bout (bf16). grid = 4096 rows, 256 threads.
// ---------------------------------------------------------------------------
__global__ __launch_bounds__(256)
void ln_kernel(const float* __restrict__ xin, const bf16_t* __restrict__ add,
               const float* __restrict__ g, const float* __restrict__ beta,
               float* __restrict__ xout, bf16_t* __restrict__ bout)
{
    __shared__ float red[8];
    const int row = blockIdx.x;
    const int t = threadIdx.x;
    const size_t base = (size_t)row * 1024 + t * 4;
    float4 xv = *(const float4*)&xin[base];
    ushort4 au = *(const ushort4*)&add[base];
    float tv[4];
    tv[0] = xv.x + bf2f(au.x);
    tv[1] = xv.y + bf2f(au.y);
    tv[2] = xv.z + bf2f(au.z);
    tv[3] = xv.w + bf2f(au.w);
    float s = tv[0] + tv[1] + tv[2] + tv[3];
    float s2 = tv[0] * tv[0] + tv[1] * tv[1] + tv[2] * tv[2] + tv[3] * tv[3];
#pragma unroll
    for (int o = 32; o; o >>= 1) { s += __shfl_xor(s, o, 64); s2 += __shfl_xor(s2, o, 64); }
    if ((t & 63) == 0) { red[t >> 6] = s; red[4 + (t >> 6)] = s2; }
    __syncthreads();
    s = red[0] + red[1] + red[2] + red[3];
    s2 = red[4] + red[5] + red[6] + red[7];
    const float mu = s * (1.f / 1024.f);
    const float var = s2 * (1.f / 1024.f) - mu * mu;
    const float rs = rsqrtf(var + 1e-5f);
    float4 gu = *(const float4*)&g[t * 4];
    float4 bu = *(const float4*)&beta[t * 4];
    float y0 = (tv[0] - mu) * rs * gu.x + bu.x;
    float y1 = (tv[1] - mu) * rs * gu.y + bu.y;
    float y2 = (tv[2] - mu) * rs * gu.z + bu.z;
    float y3 = (tv[3] - mu) * rs * gu.w + bu.w;
    float4 yo = {y0, y1, y2, y3};
    *(float4*)&xout[base] = yo;
    ushort4 ob = {f2bf(y0), f2bf(y1), f2bf(y2), f2bf(y3)};
    *(ushort4*)&bout[base] = ob;
}

__global__ __launch_bounds__(256)
void biascat_kernel(const float* __restrict__ bq, const float* __restrict__ bk,
                    const float* __restrict__ bv, float* __restrict__ o)
{
    int i = blockIdx.x * 256 + threadIdx.x;  // 0..3071
    o[i] = (i < 1024) ? bq[i] : (i < 2048) ? bk[i - 1024] : bv[i - 2048];
}

// ---------------------------------------------------------------------------

extern "C" void kernel_launch(void* const* d_in, const int* in_sizes, int n_in,
                              void* d_out, int out_size, void* d_ws, size_t ws_size,
                              hipStream_t stream)
{
    const int*   ids = (const int*)d_in[0];
    const int*   am  = (const int*)d_in[1];
    const float* emb = (const float*)d_in[2];
    const float* Wq  = (const float*)d_in[3];
    const float* Wk  = (const float*)d_in[4];
    const float* Wv  = (const float*)d_in[5];
    const float* bq  = (const float*)d_in[6];
    const float* bk  = (const float*)d_in[7];
    const float* bv  = (const float*)d_in[8];
    const float* g1  = (const float*)d_in[9];
    const float* be1 = (const float*)d_in[10];
    const float* Wf1 = (const float*)d_in[11];
    const float* bf1 = (const float*)d_in[12];
    const float* Wf2 = (const float*)d_in[13];
    const float* bf2_ = (const float*)d_in[14];
    const float* g2  = (const float*)d_in[15];
    const float* be2 = (const float*)d_in[16];

    char* ws = (char*)d_ws;
    float*  x      = (float*)(ws);                      // 16 MB  [0,16M)
    bf16_t* xb     = (bf16_t*)(ws + (16LL << 20));      // 8 MB   [16,24)
    bf16_t* qkv    = (bf16_t*)(ws + (24LL << 20));      // 24 MB  [24,48)
    bf16_t* vt     = (bf16_t*)(ws + (48LL << 20));      // 8 MB   [48,56)
    float*  scores = (float*)(ws + (56LL << 20));       // 16 MB  [56,72)  (aliases h)
    bf16_t* p      = (bf16_t*)(ws + (72LL << 20));      // 8 MB   [72,80)  (aliases h)
    bf16_t* h      = (bf16_t*)(ws + (56LL << 20));      // 32 MB  [56,88)
    bf16_t* attn   = (bf16_t*)(ws + (88LL << 20));      // 8 MB   [88,96)  (also f)
    bf16_t* wqkvT  = (bf16_t*)(ws + (96LL << 20));      // 6 MB   [96,102)
    bf16_t* wf1T   = (bf16_t*)(ws + (102LL << 20));     // 8 MB   [102,110)
    bf16_t* wf2T   = (bf16_t*)(ws + (110LL << 20));     // 8 MB   [110,118)
    float*  qbias  = (float*)(ws + (118LL << 20));      // 12 KB

    embed_kernel<<<4096, 256, 0, stream>>>(ids, emb, x, xb);

    for (int l = 0; l < 6; l++) {
        const size_t DD = 1024 * 1024;
        // weight convert-transposes: f32 [K][N] -> bf16 [N][K]
        transpose_f32_bf16<<<dim3(16, 16, 1), 256, 0, stream>>>(Wq + (size_t)l * DD, wqkvT,          1024, 1024);
        transpose_f32_bf16<<<dim3(16, 16, 1), 256, 0, stream>>>(Wk + (size_t)l * DD, wqkvT + DD,     1024, 1024);
        transpose_f32_bf16<<<dim3(16, 16, 1), 256, 0, stream>>>(Wv + (size_t)l * DD, wqkvT + 2 * DD, 1024, 1024);
        transpose_f32_bf16<<<dim3(64, 16, 1), 256, 0, stream>>>(Wf1 + (size_t)l * 4 * DD, wf1T, 4096, 1024);
        transpose_f32_bf16<<<dim3(16, 64, 1), 256, 0, stream>>>(Wf2 + (size_t)l * 4 * DD, wf2T, 1024, 4096);
        biascat_kernel<<<12, 256, 0, stream>>>(bq + l * 1024, bk + l * 1024, bv + l * 1024, qbias);

        // fused QKV: [4096,1024] x [3072,1024]^T -> qkv [4096,3072]  (256^2 kernel)
        gemm_bt8<0><<<dim3(12, 16, 1), 512, 0, stream>>>(xb, 1024, wqkvT, 1024,
                                                         qkv, 3072, qbias, 1024);
        // V^T per batch: [S,D] (ld 3072) -> [D,S]
        transpose_bf16<<<dim3(16, 16, 4), 256, 0, stream>>>(qkv + 2048, vt, 3072, 1024,
                                                            1024L * 3072, 1024L * 1024);
        // scores = Q K^T * 1/32  (f32)
        gemm_bt<2><<<dim3(8, 8, 4), 256, 0, stream>>>(qkv, 3072, 1024L * 3072,
                                                      qkv + 1024, 3072, 1024L * 3072,
                                                      scores, 1024, 1024L * 1024,
                                                      nullptr, 1024, 0.03125f);
        softmax_kernel<<<1024, 256, 0, stream>>>(scores, am, p);
        // attn = P V  (via V^T as Bt)
        gemm_bt<0><<<dim3(8, 8, 4), 256, 0, stream>>>(p, 1024, 1024L * 1024,
                                                      vt, 1024, 1024L * 1024,
                                                      attn, 1024, 1024L * 1024,
                                                      nullptr, 1024, 0.f);
        ln_kernel<<<4096, 256, 0, stream>>>(x, attn, g1 + l * 1024, be1 + l * 1024, x, xb);
        // FF1 with relu -> h [4096,4096]  (256^2 kernel)
        gemm_bt8<1><<<dim3(16, 16, 1), 512, 0, stream>>>(xb, 1024, wf1T, 1024,
                                                         h, 4096, bf1 + l * 4096, 1024);
        // FF2 -> f (reuse attn buffer) [4096,1024]
        gemm_bt<0><<<dim3(8, 32, 1), 256, 0, stream>>>(h, 4096, 0, wf2T, 4096, 0,
                                                       attn, 1024, 0, bf2_ + l * 1024, 4096, 0.f);
        float*  xo = (l == 5) ? (float*)d_out : x;
        ln_kernel<<<4096, 256, 0, stream>>>(x, attn, g2 + l * 1024, be2 + l * 1024, xo, xb);
    }
    (void)in_sizes; (void)n_in; (void)out_size; (void)ws_size;
}

// Round 5
// 1388.416 us; speedup vs baseline: 1.1505x; 1.1505x over previous
//
#include <hip/hip_runtime.h>

typedef __bf16 bf16_t;
typedef __bf16 bf16x8 __attribute__((ext_vector_type(8)));
typedef float f32x4 __attribute__((ext_vector_type(4)));
typedef unsigned short u16;

#define DEV static __device__ __forceinline__

DEV float bf2f(u16 u) { __bf16 h = __builtin_bit_cast(__bf16, u); return (float)h; }
DEV u16 f2bf(float f) { __bf16 h = (__bf16)f; return __builtin_bit_cast(u16, h); }

// async global->LDS, 16B per lane; lds base must be wave-uniform.
DEV void gll16(bf16_t* lds, const bf16_t* g) {
    __builtin_amdgcn_global_load_lds(
        (const __attribute__((address_space(1))) void*)g,
        (__attribute__((address_space(3))) void*)lds, 16, 0, 0);
}

#define WAITV(N) asm volatile("s_waitcnt vmcnt(" #N ")" ::: "memory")

// ---------------------------------------------------------------------------
// 256x256-tile GEMM, 8 waves (2M x 4N), BK=64, 4 phases/K-step, double-buffered
// 128KiB LDS, counted vmcnt (never 0 in loop), setprio around MFMA clusters.
// Per wave: 128x64 output = 8x4 frags. Swizzle: 16B-slot s of row r holds
// global slot s^(r&7) (pre-swizzled source, XOR on read) -> 0 bank conflicts.
// Buffer rotation: t+1 pairs 1..3 staged at PH1..PH3 (-> buf nxt); t+2 pair 0
// staged at PH4 (-> buf cur, whose reads completed at PH3's barrier).
// End-of-iter wait: vmcnt(2) = all of t+1 landed, t+2's pair still flying.
// EPI: 0 = bf16 out (+f32 bias if non-null), 1 = bf16 out + bias + relu
// ---------------------------------------------------------------------------
template <int EPI>
__global__ __launch_bounds__(512, 1)
void gemm8p(const bf16_t* __restrict__ A, int lda,
            const bf16_t* __restrict__ Bt, int ldb,
            bf16_t* __restrict__ C, int ldc,
            const float* __restrict__ bias, int K,
            long kadv, long cadv)
{
    __shared__ bf16_t Asm[2 * 2 * 8192];   // [buf][half][128*64]
    __shared__ bf16_t Bsm[2 * 2 * 8192];
    const int tid = threadIdx.x, w = tid >> 6, l = tid & 63;
    const int z = blockIdx.z;
    A  += (size_t)z * kadv;
    Bt += (size_t)z * kadv;
    C  += (size_t)z * cadv;

    // XCD-aware bijective swizzle (nlin % 8 == 0 for all grids used)
    const int gx = gridDim.x;
    int lin = blockIdx.y * gx + blockIdx.x;
    const int nlin = gx * gridDim.y;
    lin = (lin & 7) * (nlin >> 3) + (lin >> 3);
    const size_t row0 = (size_t)(lin / gx) * 256;
    const size_t col0 = (size_t)(lin % gx) * 256;

    const int wr = w >> 2, wc = w & 3;      // wave tile role
    const int bh = wc >> 1;                 // B half this wave reads
    const int browoff = (wc & 1) * 64;
    const int fr = l & 15, q = l >> 4, sw = l & 7;

    // staging geometry: 512 threads = 64 rows x 8 slots per issue
    const int srow = w * 8 + (l >> 3);
    const int sslot8 = ((l & 7) ^ ((l >> 3) & 7)) * 8;
    const bf16_t* AgH0 = A  + (row0 + srow) * (size_t)lda + sslot8;
    const bf16_t* BgH0 = Bt + (col0 + srow) * (size_t)ldb + sslot8;
    const size_t a128 = (size_t)128 * lda, b128 = (size_t)128 * ldb;
    const size_t a64  = (size_t)64 * lda,  b64  = (size_t)64 * ldb;
    const int wlds = w * 512;               // (w*8 rows)*64

    // stage pair p (0:Ah0 1:Ah1 2:Bh0 3:Bh1) of K-tile tt into buffer buf
#define STAGE_PAIR(buf, tt, p)                                                 \
    do {                                                                       \
        const int koff = (tt) * 64;                                            \
        if ((p) == 0) {                                                        \
            gll16(Asm + ((buf)*2+0)*8192 + wlds,        AgH0 + koff);          \
            gll16(Asm + ((buf)*2+0)*8192 + 4096 + wlds, AgH0 + koff + a64);    \
        } else if ((p) == 1) {                                                 \
            gll16(Asm + ((buf)*2+1)*8192 + wlds,        AgH0 + a128 + koff);   \
            gll16(Asm + ((buf)*2+1)*8192 + 4096 + wlds, AgH0 + a128 + koff + a64); \
        } else if ((p) == 2) {                                                 \
            gll16(Bsm + ((buf)*2+0)*8192 + wlds,        BgH0 + koff);          \
            gll16(Bsm + ((buf)*2+0)*8192 + 4096 + wlds, BgH0 + koff + b64);    \
        } else {                                                               \
            gll16(Bsm + ((buf)*2+1)*8192 + wlds,        BgH0 + b128 + koff);   \
            gll16(Bsm + ((buf)*2+1)*8192 + 4096 + wlds, BgH0 + b128 + koff + b64); \
        }                                                                      \
    } while (0)

    f32x4 acc[8][4] = {};
    const int NT = K >> 6;

    // prologue: tile 0 (all 4 pairs) + pair0 of tile 1
    STAGE_PAIR(0, 0, 0); STAGE_PAIR(0, 0, 1); STAGE_PAIR(0, 0, 2); STAGE_PAIR(0, 0, 3);
    if (NT > 1) { STAGE_PAIR(1, 1, 0); WAITV(2); } else { WAITV(0); }
    __builtin_amdgcn_sched_barrier(0);
    __builtin_amdgcn_s_barrier();

    bf16x8 aR[4][2], bR[4][2];
    for (int t = 0; t < NT; ++t) {
        const int cur = t & 1, nxt = cur ^ 1;
        const bool hasN1 = (t + 1 < NT), hasN2 = (t + 2 < NT);
        const bf16_t* Ab = Asm + (cur * 2 + wr) * 8192;
        const bf16_t* Bb = Bsm + (cur * 2 + bh) * 8192;

        // ---- PH1: A(mi0-3) + B(ni0-1); stage t+1 pair1 ----
#pragma unroll
        for (int mi = 0; mi < 4; mi++)
#pragma unroll
            for (int kk = 0; kk < 2; kk++)
                aR[mi][kk] = *(const bf16x8*)&Ab[(mi * 16 + fr) * 64 + ((kk * 4 + q) ^ sw) * 8];
#pragma unroll
        for (int ni = 0; ni < 2; ni++)
#pragma unroll
            for (int kk = 0; kk < 2; kk++)
                bR[ni][kk] = *(const bf16x8*)&Bb[(browoff + ni * 16 + fr) * 64 + ((kk * 4 + q) ^ sw) * 8];
        if (hasN1) STAGE_PAIR(nxt, t + 1, 1);
        __builtin_amdgcn_s_barrier();
        __builtin_amdgcn_s_setprio(1);
#pragma unroll
        for (int mi = 0; mi < 4; mi++)
#pragma unroll
            for (int ni = 0; ni < 2; ni++)
#pragma unroll
                for (int kk = 0; kk < 2; kk++)
                    acc[mi][ni] = __builtin_amdgcn_mfma_f32_16x16x32_bf16(aR[mi][kk], bR[ni][kk], acc[mi][ni], 0, 0, 0);
        __builtin_amdgcn_s_setprio(0);
        __builtin_amdgcn_s_barrier();

        // ---- PH2: B(ni2-3); stage t+1 pair2 ----
#pragma unroll
        for (int ni = 2; ni < 4; ni++)
#pragma unroll
            for (int kk = 0; kk < 2; kk++)
                bR[ni][kk] = *(const bf16x8*)&Bb[(browoff + ni * 16 + fr) * 64 + ((kk * 4 + q) ^ sw) * 8];
        if (hasN1) STAGE_PAIR(nxt, t + 1, 2);
        __builtin_amdgcn_s_barrier();
        __builtin_amdgcn_s_setprio(1);
#pragma unroll
        for (int mi = 0; mi < 4; mi++)
#pragma unroll
            for (int ni = 2; ni < 4; ni++)
#pragma unroll
                for (int kk = 0; kk < 2; kk++)
                    acc[mi][ni] = __builtin_amdgcn_mfma_f32_16x16x32_bf16(aR[mi][kk], bR[ni][kk], acc[mi][ni], 0, 0, 0);
        __builtin_amdgcn_s_setprio(0);
        __builtin_amdgcn_s_barrier();

        // ---- PH3: A(mi4-7); stage t+1 pair3 ----
#pragma unroll
        for (int mi = 0; mi < 4; mi++)
#pragma unroll
            for (int kk = 0; kk < 2; kk++)
                aR[mi][kk] = *(const bf16x8*)&Ab[((4 + mi) * 16 + fr) * 64 + ((kk * 4 + q) ^ sw) * 8];
        if (hasN1) STAGE_PAIR(nxt, t + 1, 3);
        __builtin_amdgcn_s_barrier();
        __builtin_amdgcn_s_setprio(1);
#pragma unroll
        for (int mi = 0; mi < 4; mi++)
#pragma unroll
            for (int ni = 0; ni < 2; ni++)
#pragma unroll
                for (int kk = 0; kk < 2; kk++)
                    acc[4 + mi][ni] = __builtin_amdgcn_mfma_f32_16x16x32_bf16(aR[mi][kk], bR[ni][kk], acc[4 + mi][ni], 0, 0, 0);
        __builtin_amdgcn_s_setprio(0);
        __builtin_amdgcn_s_barrier();

        // ---- PH4: reg-only MFMA; stage t+2 pair0 into cur; counted wait ----
        if (hasN2) STAGE_PAIR(cur, t + 2, 0);
        __builtin_amdgcn_s_setprio(1);
#pragma unroll
        for (int mi = 0; mi < 4; mi++)
#pragma unroll
            for (int ni = 2; ni < 4; ni++)
#pragma unroll
                for (int kk = 0; kk < 2; kk++)
                    acc[4 + mi][ni] = __builtin_amdgcn_mfma_f32_16x16x32_bf16(aR[mi][kk], bR[ni][kk], acc[4 + mi][ni], 0, 0, 0);
        __builtin_amdgcn_s_setprio(0);
        if (hasN1) {
            if (hasN2) { WAITV(2); } else { WAITV(0); }
            __builtin_amdgcn_sched_barrier(0);
        }
        __builtin_amdgcn_s_barrier();
    }
#undef STAGE_PAIR

    // epilogue
    const int cr = q * 4, cc = fr;
#pragma unroll
    for (int ni = 0; ni < 4; ni++) {
        size_t c = col0 + wc * 64 + ni * 16 + cc;
        float bv = bias ? bias[c] : 0.f;
#pragma unroll
        for (int mi = 0; mi < 8; mi++) {
            size_t r = row0 + wr * 128 + mi * 16 + cr;
#pragma unroll
            for (int j = 0; j < 4; j++) {
                float v = acc[mi][ni][j] + bv;
                if (EPI == 1) v = fmaxf(v, 0.f);
                C[(r + j) * ldc + c] = (bf16_t)v;
            }
        }
    }
}

// ---------------------------------------------------------------------------
// GEMM: C[M,N] = A[M,K] * Bt[N,K]^T (+bias), 128x128 tile, BK=64, 4 waves.
// XOR-swizzled LDS (conflict-free), XCD-swizzled block id.
// EPI: 0 = bf16 out (+f32 bias), 1 = + relu, 2 = f32 out * scale
// ---------------------------------------------------------------------------
template <int EPI>
__global__ __launch_bounds__(256)
void gemm_bt(const bf16_t* __restrict__ A, int lda, long sA,
             const bf16_t* __restrict__ Bt, int ldb, long sB,
             void* __restrict__ Cv, int ldc, long sC,
             const float* __restrict__ bias, int K, float scale)
{
    __shared__ bf16_t Alds[128 * 64];
    __shared__ bf16_t Blds[128 * 64];
    const int tid = threadIdx.x, w = tid >> 6, l = tid & 63;
    const int bz = blockIdx.z;

    const int gx = gridDim.x;
    int lin = blockIdx.y * gx + blockIdx.x;
    const int nlin = gx * gridDim.y;
    lin = (lin & 7) * (nlin >> 3) + (lin >> 3);
    const size_t row0 = (size_t)(lin / gx) * 128;
    const size_t col0 = (size_t)(lin % gx) * 128;

    A  += (size_t)bz * sA;
    Bt += (size_t)bz * sB;

    const int lr = l >> 3;
    const int sl = (l & 7) ^ lr;
    const bf16_t* Ag = A  + (row0 + (size_t)(w * 32) + lr) * lda + sl * 8;
    const bf16_t* Bg = Bt + (col0 + (size_t)(w * 32) + lr) * ldb + sl * 8;
    bf16_t* Al = &Alds[(w * 32) * 64];
    bf16_t* Bl = &Blds[(w * 32) * 64];

    const int wm = (w >> 1) * 64, wn = (w & 1) * 64;
    f32x4 acc[4][4] = {};

    for (int k0 = 0; k0 < K; k0 += 64) {
#pragma unroll
        for (int c = 0; c < 4; c++) {
            gll16(Al + c * 8 * 64, Ag + (size_t)(c * 8) * lda + k0);
            gll16(Bl + c * 8 * 64, Bg + (size_t)(c * 8) * ldb + k0);
        }
        __syncthreads();

#pragma unroll
        for (int ks = 0; ks < 2; ks++) {
            bf16x8 afr[4], bfr[4];
#pragma unroll
            for (int i = 0; i < 4; i++) {
                const int fr = i * 16 + (l & 15);
                const int slot = (ks * 4 + (l >> 4)) ^ (l & 7);
                afr[i] = *(const bf16x8*)&Alds[(wm + fr) * 64 + slot * 8];
                bfr[i] = *(const bf16x8*)&Blds[(wn + fr) * 64 + slot * 8];
            }
#pragma unroll
            for (int mi = 0; mi < 4; mi++)
#pragma unroll
                for (int ni = 0; ni < 4; ni++)
                    acc[mi][ni] = __builtin_amdgcn_mfma_f32_16x16x32_bf16(afr[mi], bfr[ni], acc[mi][ni], 0, 0, 0);
        }
        __syncthreads();
    }

    const int cr = (l >> 4) * 4, cc = l & 15;
    if (EPI == 2) {
        float* C = (float*)Cv + (size_t)bz * sC;
#pragma unroll
        for (int mi = 0; mi < 4; mi++)
#pragma unroll
            for (int ni = 0; ni < 4; ni++) {
                size_t r = row0 + wm + mi * 16 + cr;
                size_t c = col0 + wn + ni * 16 + cc;
#pragma unroll
                for (int j = 0; j < 4; j++)
                    C[(r + j) * ldc + c] = acc[mi][ni][j] * scale;
            }
    } else {
        bf16_t* C = (bf16_t*)Cv + (size_t)bz * sC;
#pragma unroll
        for (int ni = 0; ni < 4; ni++) {
            size_t c = col0 + wn + ni * 16 + cc;
            float bv = bias ? bias[c] : 0.f;
#pragma unroll
            for (int mi = 0; mi < 4; mi++) {
                size_t r = row0 + wm + mi * 16 + cr;
#pragma unroll
                for (int j = 0; j < 4; j++) {
                    float v = acc[mi][ni][j] + bv;
                    if (EPI == 1) v = fmaxf(v, 0.f);
                    C[(r + j) * ldc + c] = (bf16_t)v;
                }
            }
        }
    }
}

// ---------------------------------------------------------------------------
// convert-transpose: f32 in [R][C] -> bf16 out [C][R]. grid=(C/64, R/64).
// ---------------------------------------------------------------------------
__global__ __launch_bounds__(256)
void transpose_f32_bf16(const float* __restrict__ in, bf16_t* __restrict__ out,
                        int ldin, int ldout)
{
    __shared__ bf16_t t[64][72];
    const int bx = blockIdx.x * 64;
    const int by = blockIdx.y * 64;
    const int tid = threadIdx.x;
    const int cj = (tid & 15) * 4, ri = tid >> 4;
#pragma unroll
    for (int k = 0; k < 4; k++) {
        int r = ri + k * 16;
        float4 v = *(const float4*)&in[(size_t)(by + r) * ldin + bx + cj];
        ushort4 o = {f2bf(v.x), f2bf(v.y), f2bf(v.z), f2bf(v.w)};
        *(ushort4*)&t[r][cj] = o;
    }
    __syncthreads();
#pragma unroll
    for (int k = 0; k < 4; k++) {
        int i = ri + k * 16;
        ushort4 o;
        o.x = __builtin_bit_cast(u16, t[cj + 0][i]);
        o.y = __builtin_bit_cast(u16, t[cj + 1][i]);
        o.z = __builtin_bit_cast(u16, t[cj + 2][i]);
        o.w = __builtin_bit_cast(u16, t[cj + 3][i]);
        *(ushort4*)&out[(size_t)(bx + i) * ldout + by + cj] = o;
    }
}

// bf16 transpose (for V): in [R][C] (ld ldin) -> out [C][R] (ld ldout)
__global__ __launch_bounds__(256)
void transpose_bf16(const bf16_t* __restrict__ in, bf16_t* __restrict__ out,
                    int ldin, int ldout, long sin_, long sout_)
{
    __shared__ bf16_t t[64][72];
    in  += (size_t)blockIdx.z * sin_;
    out += (size_t)blockIdx.z * sout_;
    const int bx = blockIdx.x * 64;
    const int by = blockIdx.y * 64;
    const int tid = threadIdx.x;
    const int cj = (tid & 15) * 4, ri = tid >> 4;
#pragma unroll
    for (int k = 0; k < 4; k++) {
        int r = ri + k * 16;
        *(ushort4*)&t[r][cj] = *(const ushort4*)&in[(size_t)(by + r) * ldin + bx + cj];
    }
    __syncthreads();
#pragma unroll
    for (int k = 0; k < 4; k++) {
        int i = ri + k * 16;
        ushort4 o;
        o.x = __builtin_bit_cast(u16, t[cj + 0][i]);
        o.y = __builtin_bit_cast(u16, t[cj + 1][i]);
        o.z = __builtin_bit_cast(u16, t[cj + 2][i]);
        o.w = __builtin_bit_cast(u16, t[cj + 3][i]);
        *(ushort4*)&out[(size_t)(bx + i) * ldout + by + cj] = o;
    }
}

// ---------------------------------------------------------------------------
// embedding (f32 table) + sinusoidal PE -> x (f32) and xb (bf16). grid = 4096.
// ---------------------------------------------------------------------------
__global__ __launch_bounds__(256)
void embed_kernel(const int* __restrict__ ids, const float* __restrict__ emb,
                  float* __restrict__ x, bf16_t* __restrict__ xb)
{
    const int row = blockIdx.x;
    const int s = row & 1023;
    const int id = ids[row];
    const float* er = emb + (size_t)id * 1024;
    float* xr = x + (size_t)row * 1024;
    bf16_t* br = xb + (size_t)row * 1024;
#pragma unroll
    for (int k = 0; k < 2; k++) {
        int i = threadIdx.x + 256 * k;
        int d = 2 * i;
        float dv = expf((float)d * -0.008994473019508f);
        float ph = (float)s * dv;
        float sv, cv;
        sincosf(ph, &sv, &cv);
        float2 ev = *(const float2*)&er[d];
        float x0 = ev.x + sv;
        float x1 = ev.y + cv;
        float2 xo = {x0, x1};
        *(float2*)&xr[d] = xo;
        ushort2 bo = {f2bf(x0), f2bf(x1)};
        *(ushort2*)&br[d] = bo;
    }
}

// ---------------------------------------------------------------------------
// masked softmax over rows of f32 scores -> bf16 probs. One wave per row.
// ---------------------------------------------------------------------------
__global__ __launch_bounds__(256)
void softmax_kernel(const float* __restrict__ sc, const int* __restrict__ amask,
                    bf16_t* __restrict__ p)
{
    const int row = blockIdx.x * 4 + (threadIdx.x >> 6);
    const int l = threadIdx.x & 63;
    const int b = row >> 10;
    const float* s = sc + (size_t)row * 1024;
    const int* m = amask + (size_t)b * 1024;
    float v[16];
    float mx = -3.0e38f;
#pragma unroll
    for (int i = 0; i < 4; i++) {
        int c = 4 * l + 256 * i;
        float4 sv = *(const float4*)&s[c];
        int4 mv = *(const int4*)&m[c];
        v[4 * i + 0] = mv.x ? sv.x : -1e9f;
        v[4 * i + 1] = mv.y ? sv.y : -1e9f;
        v[4 * i + 2] = mv.z ? sv.z : -1e9f;
        v[4 * i + 3] = mv.w ? sv.w : -1e9f;
        mx = fmaxf(mx, fmaxf(fmaxf(v[4 * i], v[4 * i + 1]), fmaxf(v[4 * i + 2], v[4 * i + 3])));
    }
#pragma unroll
    for (int o = 32; o; o >>= 1) mx = fmaxf(mx, __shfl_xor(mx, o, 64));
    float sum = 0.f;
#pragma unroll
    for (int i = 0; i < 16; i++) { v[i] = __expf(v[i] - mx); sum += v[i]; }
#pragma unroll
    for (int o = 32; o; o >>= 1) sum += __shfl_xor(sum, o, 64);
    float inv = 1.0f / sum;
#pragma unroll
    for (int i = 0; i < 4; i++) {
        int c = 4 * l + 256 * i;
        ushort4 st;
        st.x = f2bf(v[4 * i + 0] * inv);
        st.y = f2bf(v[4 * i + 1] * inv);
        st.z = f2bf(v[4 * i + 2] * inv);
        st.w = f2bf(v[4 * i + 3] * inv);
        *(ushort4*)&p[(size_t)row * 1024 + c] = st;
    }
}

// ---------------------------------------------------------------------------
// residual + LayerNorm: t = xin + add; y = LN(t)*g + beta
// ---------------------------------------------------------------------------
__global__ __launch_bounds__(256)
void ln_kernel(const float* __restrict__ xin, const bf16_t* __restrict__ add,
               const float* __restrict__ g, const float* __restrict__ beta,
               float* __restrict__ xout, bf16_t* __restrict__ bout)
{
    __shared__ float red[8];
    const int row = blockIdx.x;
    const int t = threadIdx.x;
    const size_t base = (size_t)row * 1024 + t * 4;
    float4 xv = *(const float4*)&xin[base];
    ushort4 au = *(const ushort4*)&add[base];
    float tv[4];
    tv[0] = xv.x + bf2f(au.x);
    tv[1] = xv.y + bf2f(au.y);
    tv[2] = xv.z + bf2f(au.z);
    tv[3] = xv.w + bf2f(au.w);
    float s = tv[0] + tv[1] + tv[2] + tv[3];
    float s2 = tv[0] * tv[0] + tv[1] * tv[1] + tv[2] * tv[2] + tv[3] * tv[3];
#pragma unroll
    for (int o = 32; o; o >>= 1) { s += __shfl_xor(s, o, 64); s2 += __shfl_xor(s2, o, 64); }
    if ((t & 63) == 0) { red[t >> 6] = s; red[4 + (t >> 6)] = s2; }
    __syncthreads();
    s = red[0] + red[1] + red[2] + red[3];
    s2 = red[4] + red[5] + red[6] + red[7];
    const float mu = s * (1.f / 1024.f);
    const float var = s2 * (1.f / 1024.f) - mu * mu;
    const float rs = rsqrtf(var + 1e-5f);
    float4 gu = *(const float4*)&g[t * 4];
    float4 bu = *(const float4*)&beta[t * 4];
    float y0 = (tv[0] - mu) * rs * gu.x + bu.x;
    float y1 = (tv[1] - mu) * rs * gu.y + bu.y;
    float y2 = (tv[2] - mu) * rs * gu.z + bu.z;
    float y3 = (tv[3] - mu) * rs * gu.w + bu.w;
    float4 yo = {y0, y1, y2, y3};
    *(float4*)&xout[base] = yo;
    ushort4 ob = {f2bf(y0), f2bf(y1), f2bf(y2), f2bf(y3)};
    *(ushort4*)&bout[base] = ob;
}

// ---------------------------------------------------------------------------
// residual + 4-plane-sum + bias + LayerNorm (for split-K FF2):
// t = xin + sum_z p[z] + fbias; y = LN(t)*g + beta
// ---------------------------------------------------------------------------
__global__ __launch_bounds__(256)
void ln4_kernel(const float* __restrict__ xin, const bf16_t* __restrict__ p,
                long pstride, const float* __restrict__ fbias,
                const float* __restrict__ g, const float* __restrict__ beta,
                float* __restrict__ xout, bf16_t* __restrict__ bout)
{
    __shared__ float red[8];
    const int row = blockIdx.x;
    const int t = threadIdx.x;
    const size_t base = (size_t)row * 1024 + t * 4;
    float4 xv = *(const float4*)&xin[base];
    float4 bb = *(const float4*)&fbias[t * 4];
    float tv[4] = {xv.x + bb.x, xv.y + bb.y, xv.z + bb.z, xv.w + bb.w};
#pragma unroll
    for (int z = 0; z < 4; z++) {
        ushort4 au = *(const ushort4*)&p[(size_t)z * pstride + base];
        tv[0] += bf2f(au.x); tv[1] += bf2f(au.y);
        tv[2] += bf2f(au.z); tv[3] += bf2f(au.w);
    }
    float s = tv[0] + tv[1] + tv[2] + tv[3];
    float s2 = tv[0] * tv[0] + tv[1] * tv[1] + tv[2] * tv[2] + tv[3] * tv[3];
#pragma unroll
    for (int o = 32; o; o >>= 1) { s += __shfl_xor(s, o, 64); s2 += __shfl_xor(s2, o, 64); }
    if ((t & 63) == 0) { red[t >> 6] = s; red[4 + (t >> 6)] = s2; }
    __syncthreads();
    s = red[0] + red[1] + red[2] + red[3];
    s2 = red[4] + red[5] + red[6] + red[7];
    const float mu = s * (1.f / 1024.f);
    const float var = s2 * (1.f / 1024.f) - mu * mu;
    const float rs = rsqrtf(var + 1e-5f);
    float4 gu = *(const float4*)&g[t * 4];
    float4 bu = *(const float4*)&beta[t * 4];
    float y0 = (tv[0] - mu) * rs * gu.x + bu.x;
    float y1 = (tv[1] - mu) * rs * gu.y + bu.y;
    float y2 = (tv[2] - mu) * rs * gu.z + bu.z;
    float y3 = (tv[3] - mu) * rs * gu.w + bu.w;
    float4 yo = {y0, y1, y2, y3};
    *(float4*)&xout[base] = yo;
    ushort4 ob = {f2bf(y0), f2bf(y1), f2bf(y2), f2bf(y3)};
    *(ushort4*)&bout[base] = ob;
}

__global__ __launch_bounds__(256)
void biascat_kernel(const float* __restrict__ bq, const float* __restrict__ bk,
                    const float* __restrict__ bv, float* __restrict__ o)
{
    int i = blockIdx.x * 256 + threadIdx.x;
    o[i] = (i < 1024) ? bq[i] : (i < 2048) ? bk[i - 1024] : bv[i - 2048];
}

// ---------------------------------------------------------------------------

extern "C" void kernel_launch(void* const* d_in, const int* in_sizes, int n_in,
                              void* d_out, int out_size, void* d_ws, size_t ws_size,
                              hipStream_t stream)
{
    const int*   ids = (const int*)d_in[0];
    const int*   am  = (const int*)d_in[1];
    const float* emb = (const float*)d_in[2];
    const float* Wq  = (const float*)d_in[3];
    const float* Wk  = (const float*)d_in[4];
    const float* Wv  = (const float*)d_in[5];
    const float* bq  = (const float*)d_in[6];
    const float* bk  = (const float*)d_in[7];
    const float* bv  = (const float*)d_in[8];
    const float* g1  = (const float*)d_in[9];
    const float* be1 = (const float*)d_in[10];
    const float* Wf1 = (const float*)d_in[11];
    const float* bf1 = (const float*)d_in[12];
    const float* Wf2 = (const float*)d_in[13];
    const float* bf2_ = (const float*)d_in[14];
    const float* g2  = (const float*)d_in[15];
    const float* be2 = (const float*)d_in[16];

    char* ws = (char*)d_ws;
    float*  x      = (float*)(ws);                      // 16 MB  [0,16)
    bf16_t* xb     = (bf16_t*)(ws + (16LL << 20));      // 8 MB   [16,24)
    bf16_t* qkv    = (bf16_t*)(ws + (24LL << 20));      // 24 MB  [24,48)
    bf16_t* vt     = (bf16_t*)(ws + (48LL << 20));      // 8 MB   [48,56)
    bf16_t* fpart  = (bf16_t*)(ws + (24LL << 20));      // 32 MB  [24,56) (aliases qkv/vt, dead by FF2)
    float*  scores = (float*)(ws + (56LL << 20));       // 16 MB  [56,72) (aliases h)
    bf16_t* p      = (bf16_t*)(ws + (72LL << 20));      // 8 MB   [72,80) (aliases h)
    bf16_t* h      = (bf16_t*)(ws + (56LL << 20));      // 32 MB  [56,88)
    bf16_t* attn   = (bf16_t*)(ws + (88LL << 20));      // 8 MB   [88,96)
    bf16_t* wqkvT  = (bf16_t*)(ws + (96LL << 20));      // 6 MB   [96,102)
    bf16_t* wf1T   = (bf16_t*)(ws + (102LL << 20));     // 8 MB   [102,110)
    bf16_t* wf2T   = (bf16_t*)(ws + (110LL << 20));     // 8 MB   [110,118)
    float*  qbias  = (float*)(ws + (118LL << 20));      // 12 KB

    embed_kernel<<<4096, 256, 0, stream>>>(ids, emb, x, xb);

    for (int l = 0; l < 6; l++) {
        const size_t DD = 1024 * 1024;
        transpose_f32_bf16<<<dim3(16, 16, 1), 256, 0, stream>>>(Wq + (size_t)l * DD, wqkvT,          1024, 1024);
        transpose_f32_bf16<<<dim3(16, 16, 1), 256, 0, stream>>>(Wk + (size_t)l * DD, wqkvT + DD,     1024, 1024);
        transpose_f32_bf16<<<dim3(16, 16, 1), 256, 0, stream>>>(Wv + (size_t)l * DD, wqkvT + 2 * DD, 1024, 1024);
        transpose_f32_bf16<<<dim3(64, 16, 1), 256, 0, stream>>>(Wf1 + (size_t)l * 4 * DD, wf1T, 4096, 1024);
        transpose_f32_bf16<<<dim3(16, 64, 1), 256, 0, stream>>>(Wf2 + (size_t)l * 4 * DD, wf2T, 1024, 4096);
        biascat_kernel<<<12, 256, 0, stream>>>(bq + l * 1024, bk + l * 1024, bv + l * 1024, qbias);

        // fused QKV: [4096,1024] x [3072,1024]^T -> qkv [4096,3072]
        gemm8p<0><<<dim3(12, 16, 1), 512, 0, stream>>>(xb, 1024, wqkvT, 1024,
                                                       qkv, 3072, qbias, 1024, 0, 0);
        // V^T per batch: [S,D] (ld 3072) -> [D,S]
        transpose_bf16<<<dim3(16, 16, 4), 256, 0, stream>>>(qkv + 2048, vt, 3072, 1024,
                                                            1024L * 3072, 1024L * 1024);
        // scores = Q K^T * 1/32  (f32)
        gemm_bt<2><<<dim3(8, 8, 4), 256, 0, stream>>>(qkv, 3072, 1024L * 3072,
                                                      qkv + 1024, 3072, 1024L * 3072,
                                                      scores, 1024, 1024L * 1024,
                                                      nullptr, 1024, 0.03125f);
        softmax_kernel<<<1024, 256, 0, stream>>>(scores, am, p);
        // attn = P V  (via V^T as Bt)
        gemm_bt<0><<<dim3(8, 8, 4), 256, 0, stream>>>(p, 1024, 1024L * 1024,
                                                      vt, 1024, 1024L * 1024,
                                                      attn, 1024, 1024L * 1024,
                                                      nullptr, 1024, 0.f);
        ln_kernel<<<4096, 256, 0, stream>>>(x, attn, g1 + l * 1024, be1 + l * 1024, x, xb);
        // FF1 with relu -> h [4096,4096]
        gemm8p<1><<<dim3(16, 16, 1), 512, 0, stream>>>(xb, 1024, wf1T, 1024,
                                                       h, 4096, bf1 + l * 4096, 1024, 0, 0);
        // FF2 split-K=4: partial planes fpart[z][4096][1024] (bf16, no bias)
        gemm8p<0><<<dim3(4, 16, 4), 512, 0, stream>>>(h, 4096, wf2T, 4096,
                                                      fpart, 1024, nullptr, 1024,
                                                      1024, 4096L * 1024);
        float* xo = (l == 5) ? (float*)d_out : x;
        ln4_kernel<<<4096, 256, 0, stream>>>(x, fpart, 4096L * 1024, bf2_ + l * 1024,
                                             g2 + l * 1024, be2 + l * 1024, xo, xb);
    }
    (void)in_sizes; (void)n_in; (void)out_size; (void)ws_size;
}

// Round 6
// 1351.969 us; speedup vs baseline: 1.1815x; 1.0270x over previous
//
#include <hip/hip_runtime.h>

typedef __bf16 bf16_t;
typedef __bf16 bf16x8 __attribute__((ext_vector_type(8)));
typedef float f32x4 __attribute__((ext_vector_type(4)));
typedef unsigned short u16;

#define DEV static __device__ __forceinline__

DEV float bf2f(u16 u) { __bf16 h = __builtin_bit_cast(__bf16, u); return (float)h; }
DEV u16 f2bf(float f) { __bf16 h = (__bf16)f; return __builtin_bit_cast(u16, h); }

// async global->LDS, 16B per lane; lds base must be wave-uniform.
DEV void gll16(bf16_t* lds, const bf16_t* g) {
    __builtin_amdgcn_global_load_lds(
        (const __attribute__((address_space(1))) void*)g,
        (__attribute__((address_space(3))) void*)lds, 16, 0, 0);
}

#define WAITV(N) asm volatile("s_waitcnt vmcnt(" #N ")" ::: "memory")

// ---------------------------------------------------------------------------
// 256x256-tile GEMM, 8 waves (2M x 4N), BK=64, 4 phases/K-step, double-buffered
// 128KiB LDS, counted vmcnt (never 0 in loop), setprio around MFMA clusters.
// EPI: 0 = bf16 out (+f32 bias if non-null), 1 = bf16 out + bias + relu
// ---------------------------------------------------------------------------
template <int EPI>
__global__ __launch_bounds__(512, 1)
void gemm8p(const bf16_t* __restrict__ A, int lda,
            const bf16_t* __restrict__ Bt, int ldb,
            bf16_t* __restrict__ C, int ldc,
            const float* __restrict__ bias, int K,
            long kadv, long cadv)
{
    __shared__ bf16_t Asm[2 * 2 * 8192];   // [buf][half][128*64]
    __shared__ bf16_t Bsm[2 * 2 * 8192];
    const int tid = threadIdx.x, w = tid >> 6, l = tid & 63;
    const int z = blockIdx.z;
    A  += (size_t)z * kadv;
    Bt += (size_t)z * kadv;
    C  += (size_t)z * cadv;

    const int gx = gridDim.x;
    int lin = blockIdx.y * gx + blockIdx.x;
    const int nlin = gx * gridDim.y;
    lin = (lin & 7) * (nlin >> 3) + (lin >> 3);
    const size_t row0 = (size_t)(lin / gx) * 256;
    const size_t col0 = (size_t)(lin % gx) * 256;

    const int wr = w >> 2, wc = w & 3;
    const int bh = wc >> 1;
    const int browoff = (wc & 1) * 64;
    const int fr = l & 15, q = l >> 4, sw = l & 7;

    const int srow = w * 8 + (l >> 3);
    const int sslot8 = ((l & 7) ^ ((l >> 3) & 7)) * 8;
    const bf16_t* AgH0 = A  + (row0 + srow) * (size_t)lda + sslot8;
    const bf16_t* BgH0 = Bt + (col0 + srow) * (size_t)ldb + sslot8;
    const size_t a128 = (size_t)128 * lda, b128 = (size_t)128 * ldb;
    const size_t a64  = (size_t)64 * lda,  b64  = (size_t)64 * ldb;
    const int wlds = w * 512;

#define STAGE_PAIR(buf, tt, p)                                                 \
    do {                                                                       \
        const int koff = (tt) * 64;                                            \
        if ((p) == 0) {                                                        \
            gll16(Asm + ((buf)*2+0)*8192 + wlds,        AgH0 + koff);          \
            gll16(Asm + ((buf)*2+0)*8192 + 4096 + wlds, AgH0 + koff + a64);    \
        } else if ((p) == 1) {                                                 \
            gll16(Asm + ((buf)*2+1)*8192 + wlds,        AgH0 + a128 + koff);   \
            gll16(Asm + ((buf)*2+1)*8192 + 4096 + wlds, AgH0 + a128 + koff + a64); \
        } else if ((p) == 2) {                                                 \
            gll16(Bsm + ((buf)*2+0)*8192 + wlds,        BgH0 + koff);          \
            gll16(Bsm + ((buf)*2+0)*8192 + 4096 + wlds, BgH0 + koff + b64);    \
        } else {                                                               \
            gll16(Bsm + ((buf)*2+1)*8192 + wlds,        BgH0 + b128 + koff);   \
            gll16(Bsm + ((buf)*2+1)*8192 + 4096 + wlds, BgH0 + b128 + koff + b64); \
        }                                                                      \
    } while (0)

    f32x4 acc[8][4] = {};
    const int NT = K >> 6;

    STAGE_PAIR(0, 0, 0); STAGE_PAIR(0, 0, 1); STAGE_PAIR(0, 0, 2); STAGE_PAIR(0, 0, 3);
    if (NT > 1) { STAGE_PAIR(1, 1, 0); WAITV(2); } else { WAITV(0); }
    __builtin_amdgcn_sched_barrier(0);
    __builtin_amdgcn_s_barrier();

    bf16x8 aR[4][2], bR[4][2];
    for (int t = 0; t < NT; ++t) {
        const int cur = t & 1, nxt = cur ^ 1;
        const bool hasN1 = (t + 1 < NT), hasN2 = (t + 2 < NT);
        const bf16_t* Ab = Asm + (cur * 2 + wr) * 8192;
        const bf16_t* Bb = Bsm + (cur * 2 + bh) * 8192;

        // ---- PH1 ----
#pragma unroll
        for (int mi = 0; mi < 4; mi++)
#pragma unroll
            for (int kk = 0; kk < 2; kk++)
                aR[mi][kk] = *(const bf16x8*)&Ab[(mi * 16 + fr) * 64 + ((kk * 4 + q) ^ sw) * 8];
#pragma unroll
        for (int ni = 0; ni < 2; ni++)
#pragma unroll
            for (int kk = 0; kk < 2; kk++)
                bR[ni][kk] = *(const bf16x8*)&Bb[(browoff + ni * 16 + fr) * 64 + ((kk * 4 + q) ^ sw) * 8];
        if (hasN1) STAGE_PAIR(nxt, t + 1, 1);
        __builtin_amdgcn_s_barrier();
        __builtin_amdgcn_s_setprio(1);
#pragma unroll
        for (int mi = 0; mi < 4; mi++)
#pragma unroll
            for (int ni = 0; ni < 2; ni++)
#pragma unroll
                for (int kk = 0; kk < 2; kk++)
                    acc[mi][ni] = __builtin_amdgcn_mfma_f32_16x16x32_bf16(aR[mi][kk], bR[ni][kk], acc[mi][ni], 0, 0, 0);
        __builtin_amdgcn_s_setprio(0);
        __builtin_amdgcn_s_barrier();

        // ---- PH2 ----
#pragma unroll
        for (int ni = 2; ni < 4; ni++)
#pragma unroll
            for (int kk = 0; kk < 2; kk++)
                bR[ni][kk] = *(const bf16x8*)&Bb[(browoff + ni * 16 + fr) * 64 + ((kk * 4 + q) ^ sw) * 8];
        if (hasN1) STAGE_PAIR(nxt, t + 1, 2);
        __builtin_amdgcn_s_barrier();
        __builtin_amdgcn_s_setprio(1);
#pragma unroll
        for (int mi = 0; mi < 4; mi++)
#pragma unroll
            for (int ni = 2; ni < 4; ni++)
#pragma unroll
                for (int kk = 0; kk < 2; kk++)
                    acc[mi][ni] = __builtin_amdgcn_mfma_f32_16x16x32_bf16(aR[mi][kk], bR[ni][kk], acc[mi][ni], 0, 0, 0);
        __builtin_amdgcn_s_setprio(0);
        __builtin_amdgcn_s_barrier();

        // ---- PH3 ----
#pragma unroll
        for (int mi = 0; mi < 4; mi++)
#pragma unroll
            for (int kk = 0; kk < 2; kk++)
                aR[mi][kk] = *(const bf16x8*)&Ab[((4 + mi) * 16 + fr) * 64 + ((kk * 4 + q) ^ sw) * 8];
        if (hasN1) STAGE_PAIR(nxt, t + 1, 3);
        __builtin_amdgcn_s_barrier();
        __builtin_amdgcn_s_setprio(1);
#pragma unroll
        for (int mi = 0; mi < 4; mi++)
#pragma unroll
            for (int ni = 0; ni < 2; ni++)
#pragma unroll
                for (int kk = 0; kk < 2; kk++)
                    acc[4 + mi][ni] = __builtin_amdgcn_mfma_f32_16x16x32_bf16(aR[mi][kk], bR[ni][kk], acc[4 + mi][ni], 0, 0, 0);
        __builtin_amdgcn_s_setprio(0);
        __builtin_amdgcn_s_barrier();

        // ---- PH4 ----
        if (hasN2) STAGE_PAIR(cur, t + 2, 0);
        __builtin_amdgcn_s_setprio(1);
#pragma unroll
        for (int mi = 0; mi < 4; mi++)
#pragma unroll
            for (int ni = 2; ni < 4; ni++)
#pragma unroll
                for (int kk = 0; kk < 2; kk++)
                    acc[4 + mi][ni] = __builtin_amdgcn_mfma_f32_16x16x32_bf16(aR[mi][kk], bR[ni][kk], acc[4 + mi][ni], 0, 0, 0);
        __builtin_amdgcn_s_setprio(0);
        if (hasN1) {
            if (hasN2) { WAITV(2); } else { WAITV(0); }
            __builtin_amdgcn_sched_barrier(0);
        }
        __builtin_amdgcn_s_barrier();
    }
#undef STAGE_PAIR

    const int cr = q * 4, cc = fr;
#pragma unroll
    for (int ni = 0; ni < 4; ni++) {
        size_t c = col0 + wc * 64 + ni * 16 + cc;
        float bv = bias ? bias[c] : 0.f;
#pragma unroll
        for (int mi = 0; mi < 8; mi++) {
            size_t r = row0 + wr * 128 + mi * 16 + cr;
#pragma unroll
            for (int j = 0; j < 4; j++) {
                float v = acc[mi][ni][j] + bv;
                if (EPI == 1) v = fmaxf(v, 0.f);
                C[(r + j) * ldc + c] = (bf16_t)v;
            }
        }
    }
}

// ---------------------------------------------------------------------------
// 128x128-tile GEMM, 4 waves, BK=64, double-buffered LDS (64 KiB), counted
// vmcnt: B(t+1) staged in PH1, A(t+2) staged into cur after PH2's MFMAs,
// end-of-iter wait = vmcnt(4). Same XOR swizzle / fragment math as before.
// EPI: 0 = bf16 out (+f32 bias), 1 = + relu, 2 = f32 out * scale
// ---------------------------------------------------------------------------
template <int EPI>
__global__ __launch_bounds__(256)
void gemm_db(const bf16_t* __restrict__ A, int lda, long sA,
             const bf16_t* __restrict__ Bt, int ldb, long sB,
             void* __restrict__ Cv, int ldc, long sC,
             const float* __restrict__ bias, int K, float scale)
{
    __shared__ bf16_t Asm[2][128 * 64];
    __shared__ bf16_t Bsm[2][128 * 64];
    const int tid = threadIdx.x, w = tid >> 6, l = tid & 63;
    const int bz = blockIdx.z;

    const int gx = gridDim.x;
    int lin = blockIdx.y * gx + blockIdx.x;
    const int nlin = gx * gridDim.y;
    lin = (lin & 7) * (nlin >> 3) + (lin >> 3);
    const size_t row0 = (size_t)(lin / gx) * 128;
    const size_t col0 = (size_t)(lin % gx) * 128;

    A  += (size_t)bz * sA;
    Bt += (size_t)bz * sB;

    const int lr = l >> 3;
    const int sl = (l & 7) ^ lr;
    const bf16_t* Ag = A  + (row0 + (size_t)(w * 32) + lr) * lda + sl * 8;
    const bf16_t* Bg = Bt + (col0 + (size_t)(w * 32) + lr) * ldb + sl * 8;
    const int wlds = (w * 32) * 64;

#define STA(buf, tt)                                                           \
    do { const int ko = (tt) * 64;                                             \
        _Pragma("unroll")                                                      \
        for (int c = 0; c < 4; c++)                                            \
            gll16(&Asm[buf][wlds + c * 8 * 64], Ag + (size_t)(c * 8) * lda + ko); \
    } while (0)
#define STB(buf, tt)                                                           \
    do { const int ko = (tt) * 64;                                             \
        _Pragma("unroll")                                                      \
        for (int c = 0; c < 4; c++)                                            \
            gll16(&Bsm[buf][wlds + c * 8 * 64], Bg + (size_t)(c * 8) * ldb + ko); \
    } while (0)

    const int wm = (w >> 1) * 64, wn = (w & 1) * 64;
    const int fr16 = l & 15, q4 = l >> 4, sw = l & 7;
    f32x4 acc[4][4] = {};
    const int NT = K >> 6;

    // prologue: A(0),B(0) -> buf0; A(1) -> buf1
    STA(0, 0); STB(0, 0);
    if (NT > 1) { STA(1, 1); WAITV(4); } else { WAITV(0); }
    __builtin_amdgcn_sched_barrier(0);
    __builtin_amdgcn_s_barrier();

    for (int t = 0; t < NT; ++t) {
        const int cur = t & 1, nxt = cur ^ 1;
        const bool hasN1 = (t + 1 < NT), hasN2 = (t + 2 < NT);

        // ---- PH1: ks=0 frags; stage B(t+1) -> nxt ----
        bf16x8 a0[4], b0[4];
#pragma unroll
        for (int i = 0; i < 4; i++) {
            const int slot = (q4 ^ sw) * 8;
            a0[i] = *(const bf16x8*)&Asm[cur][(wm + i * 16 + fr16) * 64 + slot];
            b0[i] = *(const bf16x8*)&Bsm[cur][(wn + i * 16 + fr16) * 64 + slot];
        }
        if (hasN1) STB(nxt, t + 1);
        __builtin_amdgcn_s_barrier();
        __builtin_amdgcn_s_setprio(1);
#pragma unroll
        for (int mi = 0; mi < 4; mi++)
#pragma unroll
            for (int ni = 0; ni < 4; ni++)
                acc[mi][ni] = __builtin_amdgcn_mfma_f32_16x16x32_bf16(a0[mi], b0[ni], acc[mi][ni], 0, 0, 0);
        __builtin_amdgcn_s_setprio(0);
        __builtin_amdgcn_s_barrier();

        // ---- PH2: ks=1 frags; MFMA; stage A(t+2) -> cur; counted wait ----
        bf16x8 a1[4], b1[4];
#pragma unroll
        for (int i = 0; i < 4; i++) {
            const int slot = ((4 + q4) ^ sw) * 8;
            a1[i] = *(const bf16x8*)&Asm[cur][(wm + i * 16 + fr16) * 64 + slot];
            b1[i] = *(const bf16x8*)&Bsm[cur][(wn + i * 16 + fr16) * 64 + slot];
        }
        __builtin_amdgcn_s_barrier();
        __builtin_amdgcn_s_setprio(1);
#pragma unroll
        for (int mi = 0; mi < 4; mi++)
#pragma unroll
            for (int ni = 0; ni < 4; ni++)
                acc[mi][ni] = __builtin_amdgcn_mfma_f32_16x16x32_bf16(a1[mi], b1[ni], acc[mi][ni], 0, 0, 0);
        __builtin_amdgcn_s_setprio(0);
        if (hasN2) STA(cur, t + 2);
        if (hasN1) {
            if (hasN2) { WAITV(4); } else { WAITV(0); }
            __builtin_amdgcn_sched_barrier(0);
        }
        __builtin_amdgcn_s_barrier();
    }
#undef STA
#undef STB

    const int cr = q4 * 4, cc = fr16;
    if (EPI == 2) {
        float* C = (float*)Cv + (size_t)bz * sC;
#pragma unroll
        for (int mi = 0; mi < 4; mi++)
#pragma unroll
            for (int ni = 0; ni < 4; ni++) {
                size_t r = row0 + wm + mi * 16 + cr;
                size_t c = col0 + wn + ni * 16 + cc;
#pragma unroll
                for (int j = 0; j < 4; j++)
                    C[(r + j) * ldc + c] = acc[mi][ni][j] * scale;
            }
    } else {
        bf16_t* C = (bf16_t*)Cv + (size_t)bz * sC;
#pragma unroll
        for (int ni = 0; ni < 4; ni++) {
            size_t c = col0 + wn + ni * 16 + cc;
            float bv = bias ? bias[c] : 0.f;
#pragma unroll
            for (int mi = 0; mi < 4; mi++) {
                size_t r = row0 + wm + mi * 16 + cr;
#pragma unroll
                for (int j = 0; j < 4; j++) {
                    float v = acc[mi][ni][j] + bv;
                    if (EPI == 1) v = fmaxf(v, 0.f);
                    C[(r + j) * ldc + c] = (bf16_t)v;
                }
            }
        }
    }
}

// ---------------------------------------------------------------------------
// batched convert-transpose: f32 in [R][C] -> bf16 out [C][R], z-strided.
// ---------------------------------------------------------------------------
__global__ __launch_bounds__(256)
void transpose_f32_bf16(const float* __restrict__ in, bf16_t* __restrict__ out,
                        int ldin, int ldout, long sin_, long sout_)
{
    __shared__ bf16_t t[64][72];
    in  += (size_t)blockIdx.z * sin_;
    out += (size_t)blockIdx.z * sout_;
    const int bx = blockIdx.x * 64;
    const int by = blockIdx.y * 64;
    const int tid = threadIdx.x;
    const int cj = (tid & 15) * 4, ri = tid >> 4;
#pragma unroll
    for (int k = 0; k < 4; k++) {
        int r = ri + k * 16;
        float4 v = *(const float4*)&in[(size_t)(by + r) * ldin + bx + cj];
        ushort4 o = {f2bf(v.x), f2bf(v.y), f2bf(v.z), f2bf(v.w)};
        *(ushort4*)&t[r][cj] = o;
    }
    __syncthreads();
#pragma unroll
    for (int k = 0; k < 4; k++) {
        int i = ri + k * 16;
        ushort4 o;
        o.x = __builtin_bit_cast(u16, t[cj + 0][i]);
        o.y = __builtin_bit_cast(u16, t[cj + 1][i]);
        o.z = __builtin_bit_cast(u16, t[cj + 2][i]);
        o.w = __builtin_bit_cast(u16, t[cj + 3][i]);
        *(ushort4*)&out[(size_t)(bx + i) * ldout + by + cj] = o;
    }
}

// bf16 transpose (for V): in [R][C] (ld ldin) -> out [C][R] (ld ldout)
__global__ __launch_bounds__(256)
void transpose_bf16(const bf16_t* __restrict__ in, bf16_t* __restrict__ out,
                    int ldin, int ldout, long sin_, long sout_)
{
    __shared__ bf16_t t[64][72];
    in  += (size_t)blockIdx.z * sin_;
    out += (size_t)blockIdx.z * sout_;
    const int bx = blockIdx.x * 64;
    const int by = blockIdx.y * 64;
    const int tid = threadIdx.x;
    const int cj = (tid & 15) * 4, ri = tid >> 4;
#pragma unroll
    for (int k = 0; k < 4; k++) {
        int r = ri + k * 16;
        *(ushort4*)&t[r][cj] = *(const ushort4*)&in[(size_t)(by + r) * ldin + bx + cj];
    }
    __syncthreads();
#pragma unroll
    for (int k = 0; k < 4; k++) {
        int i = ri + k * 16;
        ushort4 o;
        o.x = __builtin_bit_cast(u16, t[cj + 0][i]);
        o.y = __builtin_bit_cast(u16, t[cj + 1][i]);
        o.z = __builtin_bit_cast(u16, t[cj + 2][i]);
        o.w = __builtin_bit_cast(u16, t[cj + 3][i]);
        *(ushort4*)&out[(size_t)(bx + i) * ldout + by + cj] = o;
    }
}

// ---------------------------------------------------------------------------
// embedding (f32 table) + sinusoidal PE -> x (f32) and xb (bf16). grid = 4096.
// ---------------------------------------------------------------------------
__global__ __launch_bounds__(256)
void embed_kernel(const int* __restrict__ ids, const float* __restrict__ emb,
                  float* __restrict__ x, bf16_t* __restrict__ xb)
{
    const int row = blockIdx.x;
    const int s = row & 1023;
    const int id = ids[row];
    const float* er = emb + (size_t)id * 1024;
    float* xr = x + (size_t)row * 1024;
    bf16_t* br = xb + (size_t)row * 1024;
#pragma unroll
    for (int k = 0; k < 2; k++) {
        int i = threadIdx.x + 256 * k;
        int d = 2 * i;
        float dv = expf((float)d * -0.008994473019508f);
        float ph = (float)s * dv;
        float sv, cv;
        sincosf(ph, &sv, &cv);
        float2 ev = *(const float2*)&er[d];
        float x0 = ev.x + sv;
        float x1 = ev.y + cv;
        float2 xo = {x0, x1};
        *(float2*)&xr[d] = xo;
        ushort2 bo = {f2bf(x0), f2bf(x1)};
        *(ushort2*)&br[d] = bo;
    }
}

// ---------------------------------------------------------------------------
// masked softmax over rows of f32 scores -> bf16 probs. One wave per row.
// ---------------------------------------------------------------------------
__global__ __launch_bounds__(256)
void softmax_kernel(const float* __restrict__ sc, const int* __restrict__ amask,
                    bf16_t* __restrict__ p)
{
    const int row = blockIdx.x * 4 + (threadIdx.x >> 6);
    const int l = threadIdx.x & 63;
    const int b = row >> 10;
    const float* s = sc + (size_t)row * 1024;
    const int* m = amask + (size_t)b * 1024;
    float v[16];
    float mx = -3.0e38f;
#pragma unroll
    for (int i = 0; i < 4; i++) {
        int c = 4 * l + 256 * i;
        float4 sv = *(const float4*)&s[c];
        int4 mv = *(const int4*)&m[c];
        v[4 * i + 0] = mv.x ? sv.x : -1e9f;
        v[4 * i + 1] = mv.y ? sv.y : -1e9f;
        v[4 * i + 2] = mv.z ? sv.z : -1e9f;
        v[4 * i + 3] = mv.w ? sv.w : -1e9f;
        mx = fmaxf(mx, fmaxf(fmaxf(v[4 * i], v[4 * i + 1]), fmaxf(v[4 * i + 2], v[4 * i + 3])));
    }
#pragma unroll
    for (int o = 32; o; o >>= 1) mx = fmaxf(mx, __shfl_xor(mx, o, 64));
    float sum = 0.f;
#pragma unroll
    for (int i = 0; i < 16; i++) { v[i] = __expf(v[i] - mx); sum += v[i]; }
#pragma unroll
    for (int o = 32; o; o >>= 1) sum += __shfl_xor(sum, o, 64);
    float inv = 1.0f / sum;
#pragma unroll
    for (int i = 0; i < 4; i++) {
        int c = 4 * l + 256 * i;
        ushort4 st;
        st.x = f2bf(v[4 * i + 0] * inv);
        st.y = f2bf(v[4 * i + 1] * inv);
        st.z = f2bf(v[4 * i + 2] * inv);
        st.w = f2bf(v[4 * i + 3] * inv);
        *(ushort4*)&p[(size_t)row * 1024 + c] = st;
    }
}

// ---------------------------------------------------------------------------
// residual + LayerNorm: t = xin + add; y = LN(t)*g + beta
// ---------------------------------------------------------------------------
__global__ __launch_bounds__(256)
void ln_kernel(const float* __restrict__ xin, const bf16_t* __restrict__ add,
               const float* __restrict__ g, const float* __restrict__ beta,
               float* __restrict__ xout, bf16_t* __restrict__ bout)
{
    __shared__ float red[8];
    const int row = blockIdx.x;
    const int t = threadIdx.x;
    const size_t base = (size_t)row * 1024 + t * 4;
    float4 xv = *(const float4*)&xin[base];
    ushort4 au = *(const ushort4*)&add[base];
    float tv[4];
    tv[0] = xv.x + bf2f(au.x);
    tv[1] = xv.y + bf2f(au.y);
    tv[2] = xv.z + bf2f(au.z);
    tv[3] = xv.w + bf2f(au.w);
    float s = tv[0] + tv[1] + tv[2] + tv[3];
    float s2 = tv[0] * tv[0] + tv[1] * tv[1] + tv[2] * tv[2] + tv[3] * tv[3];
#pragma unroll
    for (int o = 32; o; o >>= 1) { s += __shfl_xor(s, o, 64); s2 += __shfl_xor(s2, o, 64); }
    if ((t & 63) == 0) { red[t >> 6] = s; red[4 + (t >> 6)] = s2; }
    __syncthreads();
    s = red[0] + red[1] + red[2] + red[3];
    s2 = red[4] + red[5] + red[6] + red[7];
    const float mu = s * (1.f / 1024.f);
    const float var = s2 * (1.f / 1024.f) - mu * mu;
    const float rs = rsqrtf(var + 1e-5f);
    float4 gu = *(const float4*)&g[t * 4];
    float4 bu = *(const float4*)&beta[t * 4];
    float y0 = (tv[0] - mu) * rs * gu.x + bu.x;
    float y1 = (tv[1] - mu) * rs * gu.y + bu.y;
    float y2 = (tv[2] - mu) * rs * gu.z + bu.z;
    float y3 = (tv[3] - mu) * rs * gu.w + bu.w;
    float4 yo = {y0, y1, y2, y3};
    *(float4*)&xout[base] = yo;
    ushort4 ob = {f2bf(y0), f2bf(y1), f2bf(y2), f2bf(y3)};
    *(ushort4*)&bout[base] = ob;
}

// ---------------------------------------------------------------------------
// residual + 4-plane-sum + bias + LayerNorm (for split-K FF2)
// ---------------------------------------------------------------------------
__global__ __launch_bounds__(256)
void ln4_kernel(const float* __restrict__ xin, const bf16_t* __restrict__ p,
                long pstride, const float* __restrict__ fbias,
                const float* __restrict__ g, const float* __restrict__ beta,
                float* __restrict__ xout, bf16_t* __restrict__ bout)
{
    __shared__ float red[8];
    const int row = blockIdx.x;
    const int t = threadIdx.x;
    const size_t base = (size_t)row * 1024 + t * 4;
    float4 xv = *(const float4*)&xin[base];
    float4 bb = *(const float4*)&fbias[t * 4];
    float tv[4] = {xv.x + bb.x, xv.y + bb.y, xv.z + bb.z, xv.w + bb.w};
#pragma unroll
    for (int z = 0; z < 4; z++) {
        ushort4 au = *(const ushort4*)&p[(size_t)z * pstride + base];
        tv[0] += bf2f(au.x); tv[1] += bf2f(au.y);
        tv[2] += bf2f(au.z); tv[3] += bf2f(au.w);
    }
    float s = tv[0] + tv[1] + tv[2] + tv[3];
    float s2 = tv[0] * tv[0] + tv[1] * tv[1] + tv[2] * tv[2] + tv[3] * tv[3];
#pragma unroll
    for (int o = 32; o; o >>= 1) { s += __shfl_xor(s, o, 64); s2 += __shfl_xor(s2, o, 64); }
    if ((t & 63) == 0) { red[t >> 6] = s; red[4 + (t >> 6)] = s2; }
    __syncthreads();
    s = red[0] + red[1] + red[2] + red[3];
    s2 = red[4] + red[5] + red[6] + red[7];
    const float mu = s * (1.f / 1024.f);
    const float var = s2 * (1.f / 1024.f) - mu * mu;
    const float rs = rsqrtf(var + 1e-5f);
    float4 gu = *(const float4*)&g[t * 4];
    float4 bu = *(const float4*)&beta[t * 4];
    float y0 = (tv[0] - mu) * rs * gu.x + bu.x;
    float y1 = (tv[1] - mu) * rs * gu.y + bu.y;
    float y2 = (tv[2] - mu) * rs * gu.z + bu.z;
    float y3 = (tv[3] - mu) * rs * gu.w + bu.w;
    float4 yo = {y0, y1, y2, y3};
    *(float4*)&xout[base] = yo;
    ushort4 ob = {f2bf(y0), f2bf(y1), f2bf(y2), f2bf(y3)};
    *(ushort4*)&bout[base] = ob;
}

// all-layer bias concat: out[l*3072 + j] from bq/bk/bv[l*1024 + ...]
__global__ __launch_bounds__(256)
void biascat6_kernel(const float* __restrict__ bq, const float* __restrict__ bk,
                     const float* __restrict__ bv, float* __restrict__ o)
{
    int i = blockIdx.x * 256 + threadIdx.x;   // 0..18431
    int lyr = i / 3072, j = i - lyr * 3072;
    o[i] = (j < 1024) ? bq[lyr * 1024 + j]
         : (j < 2048) ? bk[lyr * 1024 + j - 1024]
                      : bv[lyr * 1024 + j - 2048];
}

// ---------------------------------------------------------------------------

extern "C" void kernel_launch(void* const* d_in, const int* in_sizes, int n_in,
                              void* d_out, int out_size, void* d_ws, size_t ws_size,
                              hipStream_t stream)
{
    const int*   ids = (const int*)d_in[0];
    const int*   am  = (const int*)d_in[1];
    const float* emb = (const float*)d_in[2];
    const float* Wq  = (const float*)d_in[3];
    const float* Wk  = (const float*)d_in[4];
    const float* Wv  = (const float*)d_in[5];
    const float* bq  = (const float*)d_in[6];
    const float* bk  = (const float*)d_in[7];
    const float* bv  = (const float*)d_in[8];
    const float* g1  = (const float*)d_in[9];
    const float* be1 = (const float*)d_in[10];
    const float* Wf1 = (const float*)d_in[11];
    const float* bf1 = (const float*)d_in[12];
    const float* Wf2 = (const float*)d_in[13];
    const float* bf2_ = (const float*)d_in[14];
    const float* g2  = (const float*)d_in[15];
    const float* be2 = (const float*)d_in[16];

    char* ws = (char*)d_ws;
    float*  x      = (float*)(ws);                      // 16 MB  [0,16)
    bf16_t* xb     = (bf16_t*)(ws + (16LL << 20));      // 8 MB   [16,24)
    bf16_t* qkv    = (bf16_t*)(ws + (24LL << 20));      // 24 MB  [24,48)
    bf16_t* vt     = (bf16_t*)(ws + (48LL << 20));      // 8 MB   [48,56)
    bf16_t* fpart  = (bf16_t*)(ws + (24LL << 20));      // 32 MB  [24,56) (aliases qkv/vt, dead by FF2)
    float*  scores = (float*)(ws + (56LL << 20));       // 16 MB  [56,72) (aliases h)
    bf16_t* p      = (bf16_t*)(ws + (72LL << 20));      // 8 MB   [72,80) (aliases h)
    bf16_t* h      = (bf16_t*)(ws + (56LL << 20));      // 32 MB  [56,88)
    bf16_t* attn   = (bf16_t*)(ws + (88LL << 20));      // 8 MB   [88,96)
    bf16_t* wqkvTA = (bf16_t*)(ws + (96LL << 20));      // 36 MB  [96,132)  6 layers x [3072][1024]
    bf16_t* wf1TA  = (bf16_t*)(ws + (132LL << 20));     // 48 MB  [132,180) 6 x [4096][1024]
    bf16_t* wf2TA  = (bf16_t*)(ws + (180LL << 20));     // 48 MB  [180,228) 6 x [1024][4096]
    float*  qbiasA = (float*)(ws + (228LL << 20));      // 72 KB

    const size_t DD = 1024 * 1024;

    // ---- one-time preprocessing: all 6 layers, 6 launches total ----
    transpose_f32_bf16<<<dim3(16, 16, 6), 256, 0, stream>>>(Wq, wqkvTA,          1024, 1024, (long)DD, 3L * DD);
    transpose_f32_bf16<<<dim3(16, 16, 6), 256, 0, stream>>>(Wk, wqkvTA + DD,     1024, 1024, (long)DD, 3L * DD);
    transpose_f32_bf16<<<dim3(16, 16, 6), 256, 0, stream>>>(Wv, wqkvTA + 2 * DD, 1024, 1024, (long)DD, 3L * DD);
    transpose_f32_bf16<<<dim3(64, 16, 6), 256, 0, stream>>>(Wf1, wf1TA, 4096, 1024, 4L * DD, 4L * DD);
    transpose_f32_bf16<<<dim3(16, 64, 6), 256, 0, stream>>>(Wf2, wf2TA, 1024, 4096, 4L * DD, 4L * DD);
    biascat6_kernel<<<72, 256, 0, stream>>>(bq, bk, bv, qbiasA);

    embed_kernel<<<4096, 256, 0, stream>>>(ids, emb, x, xb);

    for (int l = 0; l < 6; l++) {
        // fused QKV: [4096,1024] x [3072,1024]^T -> qkv [4096,3072]
        gemm8p<0><<<dim3(12, 16, 1), 512, 0, stream>>>(xb, 1024, wqkvTA + (size_t)l * 3 * DD, 1024,
                                                       qkv, 3072, qbiasA + l * 3072, 1024, 0, 0);
        // V^T per batch: [S,D] (ld 3072) -> [D,S]
        transpose_bf16<<<dim3(16, 16, 4), 256, 0, stream>>>(qkv + 2048, vt, 3072, 1024,
                                                            1024L * 3072, 1024L * 1024);
        // scores = Q K^T * 1/32  (f32)
        gemm_db<2><<<dim3(8, 8, 4), 256, 0, stream>>>(qkv, 3072, 1024L * 3072,
                                                      qkv + 1024, 3072, 1024L * 3072,
                                                      scores, 1024, 1024L * 1024,
                                                      nullptr, 1024, 0.03125f);
        softmax_kernel<<<1024, 256, 0, stream>>>(scores, am, p);
        // attn = P V  (via V^T as Bt)
        gemm_db<0><<<dim3(8, 8, 4), 256, 0, stream>>>(p, 1024, 1024L * 1024,
                                                      vt, 1024, 1024L * 1024,
                                                      attn, 1024, 1024L * 1024,
                                                      nullptr, 1024, 0.f);
        ln_kernel<<<4096, 256, 0, stream>>>(x, attn, g1 + l * 1024, be1 + l * 1024, x, xb);
        // FF1 with relu -> h [4096,4096]
        gemm8p<1><<<dim3(16, 16, 1), 512, 0, stream>>>(xb, 1024, wf1TA + (size_t)l * 4 * DD, 1024,
                                                       h, 4096, bf1 + l * 4096, 1024, 0, 0);
        // FF2 split-K=4: partial planes fpart[z][4096][1024] (bf16, no bias)
        gemm8p<0><<<dim3(4, 16, 4), 512, 0, stream>>>(h, 4096, wf2TA + (size_t)l * 4 * DD, 4096,
                                                      fpart, 1024, nullptr, 1024,
                                                      1024, 4096L * 1024);
        float* xo = (l == 5) ? (float*)d_out : x;
        ln4_kernel<<<4096, 256, 0, stream>>>(x, fpart, 4096L * 1024, bf2_ + l * 1024,
                                             g2 + l * 1024, be2 + l * 1024, xo, xb);
    }
    (void)in_sizes; (void)n_in; (void)out_size; (void)ws_size;
}

// Round 7
// 1273.829 us; speedup vs baseline: 1.2540x; 1.0613x over previous
//
#include <hip/hip_runtime.h>

typedef __bf16 bf16_t;
typedef __bf16 bf16x8 __attribute__((ext_vector_type(8)));
typedef float f32x4 __attribute__((ext_vector_type(4)));
typedef unsigned short u16;

#define DEV static __device__ __forceinline__

DEV float bf2f(u16 u) { __bf16 h = __builtin_bit_cast(__bf16, u); return (float)h; }
DEV u16 f2bf(float f) { __bf16 h = (__bf16)f; return __builtin_bit_cast(u16, h); }

// async global->LDS, 16B per lane; lds base must be wave-uniform.
DEV void gll16(bf16_t* lds, const bf16_t* g) {
    __builtin_amdgcn_global_load_lds(
        (const __attribute__((address_space(1))) void*)g,
        (__attribute__((address_space(3))) void*)lds, 16, 0, 0);
}

#define WAITV(N) asm volatile("s_waitcnt vmcnt(" #N ")" ::: "memory")

// ---------------------------------------------------------------------------
// 256x256-tile GEMM, 8 waves (2M x 4N), BK=64, double-buffered 128KiB LDS.
// TWO barriers per K-tile only: (mid) protects stage-into-cur after all reads
// of cur are drained; (end) publishes buffer t+1. Counted vmcnt: WAITV(2)
// leaves t+2's first pair in flight; never 0 in steady state. Waves free-run
// between barriers so ds_read and MFMA overlap across waves.
// EPI: 0 = bf16 out (+f32 bias if non-null), 1 = bf16 out + bias + relu
// ---------------------------------------------------------------------------
template <int EPI>
__global__ __launch_bounds__(512, 1)
void gemm8p(const bf16_t* __restrict__ A, int lda,
            const bf16_t* __restrict__ Bt, int ldb,
            bf16_t* __restrict__ C, int ldc,
            const float* __restrict__ bias, int K,
            long kadv, long cadv)
{
    __shared__ bf16_t Asm[2 * 2 * 8192];   // [buf][half][128*64]
    __shared__ bf16_t Bsm[2 * 2 * 8192];
    const int tid = threadIdx.x, w = tid >> 6, l = tid & 63;
    const int z = blockIdx.z;
    A  += (size_t)z * kadv;
    Bt += (size_t)z * kadv;
    C  += (size_t)z * cadv;

    const int gx = gridDim.x;
    int lin = blockIdx.y * gx + blockIdx.x;
    const int nlin = gx * gridDim.y;
    lin = (lin & 7) * (nlin >> 3) + (lin >> 3);
    const size_t row0 = (size_t)(lin / gx) * 256;
    const size_t col0 = (size_t)(lin % gx) * 256;

    const int wr = w >> 2, wc = w & 3;
    const int bh = wc >> 1;
    const int browoff = (wc & 1) * 64;
    const int fr = l & 15, q = l >> 4, sw = l & 7;

    const int srow = w * 8 + (l >> 3);
    const int sslot8 = ((l & 7) ^ ((l >> 3) & 7)) * 8;
    const bf16_t* AgH0 = A  + (row0 + srow) * (size_t)lda + sslot8;
    const bf16_t* BgH0 = Bt + (col0 + srow) * (size_t)ldb + sslot8;
    const size_t a128 = (size_t)128 * lda, b128 = (size_t)128 * ldb;
    const size_t a64  = (size_t)64 * lda,  b64  = (size_t)64 * ldb;
    const int wlds = w * 512;

#define STAGE_PAIR(buf, tt, p)                                                 \
    do {                                                                       \
        const int koff = (tt) * 64;                                            \
        if ((p) == 0) {                                                        \
            gll16(Asm + ((buf)*2+0)*8192 + wlds,        AgH0 + koff);          \
            gll16(Asm + ((buf)*2+0)*8192 + 4096 + wlds, AgH0 + koff + a64);    \
        } else if ((p) == 1) {                                                 \
            gll16(Asm + ((buf)*2+1)*8192 + wlds,        AgH0 + a128 + koff);   \
            gll16(Asm + ((buf)*2+1)*8192 + 4096 + wlds, AgH0 + a128 + koff + a64); \
        } else if ((p) == 2) {                                                 \
            gll16(Bsm + ((buf)*2+0)*8192 + wlds,        BgH0 + koff);          \
            gll16(Bsm + ((buf)*2+0)*8192 + 4096 + wlds, BgH0 + koff + b64);    \
        } else {                                                               \
            gll16(Bsm + ((buf)*2+1)*8192 + wlds,        BgH0 + b128 + koff);   \
            gll16(Bsm + ((buf)*2+1)*8192 + 4096 + wlds, BgH0 + b128 + koff + b64); \
        }                                                                      \
    } while (0)

    f32x4 acc[8][4] = {};
    const int NT = K >> 6;

    STAGE_PAIR(0, 0, 0); STAGE_PAIR(0, 0, 1); STAGE_PAIR(0, 0, 2); STAGE_PAIR(0, 0, 3);
    if (NT > 1) { STAGE_PAIR(1, 1, 0); WAITV(2); } else { WAITV(0); }
    __builtin_amdgcn_sched_barrier(0);
    __builtin_amdgcn_s_barrier();

    for (int t = 0; t < NT; ++t) {
        const int cur = t & 1, nxt = cur ^ 1;
        const bool hasN1 = (t + 1 < NT), hasN2 = (t + 2 < NT);
        const bf16_t* Ab = Asm + (cur * 2 + wr) * 8192;
        const bf16_t* Bb = Bsm + (cur * 2 + bh) * 8192;

        // region 1: read A(mi0-3) + B(all); stage t+1 pairs 1,2; 32 MFMA
        bf16x8 aR[4][2], bR[4][2];
#pragma unroll
        for (int mi = 0; mi < 4; mi++)
#pragma unroll
            for (int kk = 0; kk < 2; kk++)
                aR[mi][kk] = *(const bf16x8*)&Ab[(mi * 16 + fr) * 64 + ((kk * 4 + q) ^ sw) * 8];
#pragma unroll
        for (int ni = 0; ni < 4; ni++)
#pragma unroll
            for (int kk = 0; kk < 2; kk++)
                bR[ni][kk] = *(const bf16x8*)&Bb[(browoff + ni * 16 + fr) * 64 + ((kk * 4 + q) ^ sw) * 8];
        if (hasN1) { STAGE_PAIR(nxt, t + 1, 1); STAGE_PAIR(nxt, t + 1, 2); }
        __builtin_amdgcn_s_setprio(1);
#pragma unroll
        for (int mi = 0; mi < 4; mi++)
#pragma unroll
            for (int ni = 0; ni < 4; ni++)
#pragma unroll
                for (int kk = 0; kk < 2; kk++)
                    acc[mi][ni] = __builtin_amdgcn_mfma_f32_16x16x32_bf16(aR[mi][kk], bR[ni][kk], acc[mi][ni], 0, 0, 0);
        __builtin_amdgcn_s_setprio(0);

        // region 2: read A(mi4-7); stage t+1 pair 3; 32 MFMA
        bf16x8 a2[4][2];
#pragma unroll
        for (int mi = 0; mi < 4; mi++)
#pragma unroll
            for (int kk = 0; kk < 2; kk++)
                a2[mi][kk] = *(const bf16x8*)&Ab[((4 + mi) * 16 + fr) * 64 + ((kk * 4 + q) ^ sw) * 8];
        if (hasN1) STAGE_PAIR(nxt, t + 1, 3);
        __builtin_amdgcn_s_setprio(1);
#pragma unroll
        for (int mi = 0; mi < 4; mi++)
#pragma unroll
            for (int ni = 0; ni < 4; ni++)
#pragma unroll
                for (int kk = 0; kk < 2; kk++)
                    acc[4 + mi][ni] = __builtin_amdgcn_mfma_f32_16x16x32_bf16(a2[mi][kk], bR[ni][kk], acc[4 + mi][ni], 0, 0, 0);
        __builtin_amdgcn_s_setprio(0);

        // mid barrier: all reads of cur drained (lgkmcnt'd by their MFMAs)
        __builtin_amdgcn_s_barrier();
        if (hasN2) STAGE_PAIR(cur, t + 2, 0);
        if (hasN1) {
            if (hasN2) { WAITV(2); } else { WAITV(0); }
            __builtin_amdgcn_sched_barrier(0);
        }
        __builtin_amdgcn_s_barrier();      // t+1 buffer published
    }
#undef STAGE_PAIR

    const int cr = q * 4, cc = fr;
#pragma unroll
    for (int ni = 0; ni < 4; ni++) {
        size_t c = col0 + wc * 64 + ni * 16 + cc;
        float bv = bias ? bias[c] : 0.f;
#pragma unroll
        for (int mi = 0; mi < 8; mi++) {
            size_t r = row0 + wr * 128 + mi * 16 + cr;
#pragma unroll
            for (int j = 0; j < 4; j++) {
                float v = acc[mi][ni][j] + bv;
                if (EPI == 1) v = fmaxf(v, 0.f);
                C[(r + j) * ldc + c] = (bf16_t)v;
            }
        }
    }
}

// ---------------------------------------------------------------------------
// 128x128-tile GEMM, 4 waves, BK=64, double-buffered LDS (64 KiB), 2 barriers
// per K-tile, counted vmcnt(4). EPI: 0 bf16+bias, 1 +relu, 2 f32*scale
// ---------------------------------------------------------------------------
template <int EPI>
__global__ __launch_bounds__(256)
void gemm_db(const bf16_t* __restrict__ A, int lda, long sA,
             const bf16_t* __restrict__ Bt, int ldb, long sB,
             void* __restrict__ Cv, int ldc, long sC,
             const float* __restrict__ bias, int K, float scale)
{
    __shared__ bf16_t Asm[2][128 * 64];
    __shared__ bf16_t Bsm[2][128 * 64];
    const int tid = threadIdx.x, w = tid >> 6, l = tid & 63;
    const int bz = blockIdx.z;

    const int gx = gridDim.x;
    int lin = blockIdx.y * gx + blockIdx.x;
    const int nlin = gx * gridDim.y;
    lin = (lin & 7) * (nlin >> 3) + (lin >> 3);
    const size_t row0 = (size_t)(lin / gx) * 128;
    const size_t col0 = (size_t)(lin % gx) * 128;

    A  += (size_t)bz * sA;
    Bt += (size_t)bz * sB;

    const int lr = l >> 3;
    const int sl = (l & 7) ^ lr;
    const bf16_t* Ag = A  + (row0 + (size_t)(w * 32) + lr) * lda + sl * 8;
    const bf16_t* Bg = Bt + (col0 + (size_t)(w * 32) + lr) * ldb + sl * 8;
    const int wlds = (w * 32) * 64;

#define STA(buf, tt)                                                           \
    do { const int ko = (tt) * 64;                                             \
        _Pragma("unroll")                                                      \
        for (int c = 0; c < 4; c++)                                            \
            gll16(&Asm[buf][wlds + c * 8 * 64], Ag + (size_t)(c * 8) * lda + ko); \
    } while (0)
#define STB(buf, tt)                                                           \
    do { const int ko = (tt) * 64;                                             \
        _Pragma("unroll")                                                      \
        for (int c = 0; c < 4; c++)                                            \
            gll16(&Bsm[buf][wlds + c * 8 * 64], Bg + (size_t)(c * 8) * ldb + ko); \
    } while (0)

    const int wm = (w >> 1) * 64, wn = (w & 1) * 64;
    const int fr16 = l & 15, q4 = l >> 4, sw = l & 7;
    f32x4 acc[4][4] = {};
    const int NT = K >> 6;

    STA(0, 0); STB(0, 0);
    if (NT > 1) { STA(1, 1); WAITV(4); } else { WAITV(0); }
    __builtin_amdgcn_sched_barrier(0);
    __builtin_amdgcn_s_barrier();

    for (int t = 0; t < NT; ++t) {
        const int cur = t & 1, nxt = cur ^ 1;
        const bool hasN1 = (t + 1 < NT), hasN2 = (t + 2 < NT);

        bf16x8 a0[4], b0[4], a1[4], b1[4];
        const int s0 = (q4 ^ sw) * 8, s1 = ((4 + q4) ^ sw) * 8;
#pragma unroll
        for (int i = 0; i < 4; i++) {
            a0[i] = *(const bf16x8*)&Asm[cur][(wm + i * 16 + fr16) * 64 + s0];
            b0[i] = *(const bf16x8*)&Bsm[cur][(wn + i * 16 + fr16) * 64 + s0];
        }
        if (hasN1) STB(nxt, t + 1);
        __builtin_amdgcn_s_setprio(1);
#pragma unroll
        for (int mi = 0; mi < 4; mi++)
#pragma unroll
            for (int ni = 0; ni < 4; ni++)
                acc[mi][ni] = __builtin_amdgcn_mfma_f32_16x16x32_bf16(a0[mi], b0[ni], acc[mi][ni], 0, 0, 0);
        __builtin_amdgcn_s_setprio(0);
#pragma unroll
        for (int i = 0; i < 4; i++) {
            a1[i] = *(const bf16x8*)&Asm[cur][(wm + i * 16 + fr16) * 64 + s1];
            b1[i] = *(const bf16x8*)&Bsm[cur][(wn + i * 16 + fr16) * 64 + s1];
        }
        __builtin_amdgcn_s_setprio(1);
#pragma unroll
        for (int mi = 0; mi < 4; mi++)
#pragma unroll
            for (int ni = 0; ni < 4; ni++)
                acc[mi][ni] = __builtin_amdgcn_mfma_f32_16x16x32_bf16(a1[mi], b1[ni], acc[mi][ni], 0, 0, 0);
        __builtin_amdgcn_s_setprio(0);

        __builtin_amdgcn_s_barrier();      // reads of cur drained
        if (hasN2) STA(cur, t + 2);
        if (hasN1) {
            if (hasN2) { WAITV(4); } else { WAITV(0); }
            __builtin_amdgcn_sched_barrier(0);
        }
        __builtin_amdgcn_s_barrier();
    }
#undef STA
#undef STB

    const int cr = q4 * 4, cc = fr16;
    if (EPI == 2) {
        float* C = (float*)Cv + (size_t)bz * sC;
#pragma unroll
        for (int mi = 0; mi < 4; mi++)
#pragma unroll
            for (int ni = 0; ni < 4; ni++) {
                size_t r = row0 + wm + mi * 16 + cr;
                size_t c = col0 + wn + ni * 16 + cc;
#pragma unroll
                for (int j = 0; j < 4; j++)
                    C[(r + j) * ldc + c] = acc[mi][ni][j] * scale;
            }
    } else {
        bf16_t* C = (bf16_t*)Cv + (size_t)bz * sC;
#pragma unroll
        for (int ni = 0; ni < 4; ni++) {
            size_t c = col0 + wn + ni * 16 + cc;
            float bv = bias ? bias[c] : 0.f;
#pragma unroll
            for (int mi = 0; mi < 4; mi++) {
                size_t r = row0 + wm + mi * 16 + cr;
#pragma unroll
                for (int j = 0; j < 4; j++) {
                    float v = acc[mi][ni][j] + bv;
                    if (EPI == 1) v = fmaxf(v, 0.f);
                    C[(r + j) * ldc + c] = (bf16_t)v;
                }
            }
        }
    }
}

// ---------------------------------------------------------------------------
// one-shot preprocessing: all weight convert-transposes + bias concat + embed.
// grid regions: [0,16896) transpose tiles; [16896,16968) bias; rest embed.
// ---------------------------------------------------------------------------
__global__ __launch_bounds__(256)
void prep_kernel(const float* __restrict__ Wq, const float* __restrict__ Wk,
                 const float* __restrict__ Wv, const float* __restrict__ Wf1,
                 const float* __restrict__ Wf2,
                 const float* __restrict__ bq, const float* __restrict__ bk,
                 const float* __restrict__ bv,
                 const int* __restrict__ ids, const float* __restrict__ emb,
                 bf16_t* __restrict__ wqkvTA, bf16_t* __restrict__ wf1TA,
                 bf16_t* __restrict__ wf2TA, float* __restrict__ qbiasA,
                 float* __restrict__ x, bf16_t* __restrict__ xb)
{
    __shared__ bf16_t tls[64][72];
    const size_t DD = 1024 * 1024;
    int id = blockIdx.x;
    if (id < 16896) {
        const float* src; bf16_t* dst; int ldin, ldout, bx, by;
        if (id < 4608) {
            int layer = id / 768, r = id % 768, which = r >> 8, t = r & 255;
            src = (which == 0 ? Wq : which == 1 ? Wk : Wv) + (size_t)layer * DD;
            dst = wqkvTA + (size_t)layer * 3 * DD + (size_t)which * DD;
            ldin = 1024; ldout = 1024; bx = (t & 15) * 64; by = (t >> 4) * 64;
        } else if (id < 10752) {
            int i = id - 4608, layer = i >> 10, t = i & 1023;
            src = Wf1 + (size_t)layer * 4 * DD; dst = wf1TA + (size_t)layer * 4 * DD;
            ldin = 4096; ldout = 1024; bx = (t & 63) * 64; by = (t >> 6) * 64;
        } else {
            int i = id - 10752, layer = i >> 10, t = i & 1023;
            src = Wf2 + (size_t)layer * 4 * DD; dst = wf2TA + (size_t)layer * 4 * DD;
            ldin = 1024; ldout = 4096; bx = (t & 15) * 64; by = (t >> 4) * 64;
        }
        const int tid = threadIdx.x;
        const int cj = (tid & 15) * 4, ri = tid >> 4;
#pragma unroll
        for (int k = 0; k < 4; k++) {
            int r = ri + k * 16;
            float4 v = *(const float4*)&src[(size_t)(by + r) * ldin + bx + cj];
            ushort4 o = {f2bf(v.x), f2bf(v.y), f2bf(v.z), f2bf(v.w)};
            *(ushort4*)&tls[r][cj] = o;
        }
        __syncthreads();
#pragma unroll
        for (int k = 0; k < 4; k++) {
            int i2 = ri + k * 16;
            ushort4 o;
            o.x = __builtin_bit_cast(u16, tls[cj + 0][i2]);
            o.y = __builtin_bit_cast(u16, tls[cj + 1][i2]);
            o.z = __builtin_bit_cast(u16, tls[cj + 2][i2]);
            o.w = __builtin_bit_cast(u16, tls[cj + 3][i2]);
            *(ushort4*)&dst[(size_t)(bx + i2) * ldout + by + cj] = o;
        }
        return;
    }
    id -= 16896;
    if (id < 72) {
        int i = id * 256 + threadIdx.x;      // 0..18431
        int lyr = i / 3072, j = i - lyr * 3072;
        qbiasA[i] = (j < 1024) ? bq[lyr * 1024 + j]
                  : (j < 2048) ? bk[lyr * 1024 + j - 1024]
                               : bv[lyr * 1024 + j - 2048];
        return;
    }
    id -= 72;
    const int row = id;                       // 0..4095
    const int s = row & 1023;
    const int eid = ids[row];
    const float* er = emb + (size_t)eid * 1024;
    float* xr = x + (size_t)row * 1024;
    bf16_t* br = xb + (size_t)row * 1024;
#pragma unroll
    for (int k = 0; k < 2; k++) {
        int i = threadIdx.x + 256 * k;
        int d = 2 * i;
        float dv = expf((float)d * -0.008994473019508f);
        float ph = (float)s * dv;
        float sv, cv;
        sincosf(ph, &sv, &cv);
        float2 ev = *(const float2*)&er[d];
        float x0 = ev.x + sv;
        float x1 = ev.y + cv;
        float2 xo = {x0, x1};
        *(float2*)&xr[d] = xo;
        ushort2 bo = {f2bf(x0), f2bf(x1)};
        *(ushort2*)&br[d] = bo;
    }
}

// ---------------------------------------------------------------------------
// merged masked-softmax (blocks 0..1023, 4 rows each) + V^T transpose
// (blocks 1024..2047: 256 tiles x 4 batches).
// ---------------------------------------------------------------------------
__global__ __launch_bounds__(256)
void softvt_kernel(const float* __restrict__ sc, const int* __restrict__ amask,
                   bf16_t* __restrict__ p, const bf16_t* __restrict__ qkv,
                   bf16_t* __restrict__ vt)
{
    __shared__ bf16_t tls[64][72];
    int bid = blockIdx.x;
    if (bid < 1024) {
        const int row = bid * 4 + (threadIdx.x >> 6);
        const int l = threadIdx.x & 63;
        const int b = row >> 10;
        const float* s = sc + (size_t)row * 1024;
        const int* m = amask + (size_t)b * 1024;
        float v[16];
        float mx = -3.0e38f;
#pragma unroll
        for (int i = 0; i < 4; i++) {
            int c = 4 * l + 256 * i;
            float4 sv = *(const float4*)&s[c];
            int4 mv = *(const int4*)&m[c];
            v[4 * i + 0] = mv.x ? sv.x : -1e9f;
            v[4 * i + 1] = mv.y ? sv.y : -1e9f;
            v[4 * i + 2] = mv.z ? sv.z : -1e9f;
            v[4 * i + 3] = mv.w ? sv.w : -1e9f;
            mx = fmaxf(mx, fmaxf(fmaxf(v[4 * i], v[4 * i + 1]), fmaxf(v[4 * i + 2], v[4 * i + 3])));
        }
#pragma unroll
        for (int o = 32; o; o >>= 1) mx = fmaxf(mx, __shfl_xor(mx, o, 64));
        float sum = 0.f;
#pragma unroll
        for (int i = 0; i < 16; i++) { v[i] = __expf(v[i] - mx); sum += v[i]; }
#pragma unroll
        for (int o = 32; o; o >>= 1) sum += __shfl_xor(sum, o, 64);
        float inv = 1.0f / sum;
#pragma unroll
        for (int i = 0; i < 4; i++) {
            int c = 4 * l + 256 * i;
            ushort4 st;
            st.x = f2bf(v[4 * i + 0] * inv);
            st.y = f2bf(v[4 * i + 1] * inv);
            st.z = f2bf(v[4 * i + 2] * inv);
            st.w = f2bf(v[4 * i + 3] * inv);
            *(ushort4*)&p[(size_t)row * 1024 + c] = st;
        }
        return;
    }
    bid -= 1024;
    const int z = bid >> 8, t = bid & 255;
    const bf16_t* in = qkv + 2048 + (size_t)z * 1024 * 3072;
    bf16_t* out = vt + (size_t)z * 1024 * 1024;
    const int bx = (t & 15) * 64, by = (t >> 4) * 64;
    const int tid = threadIdx.x;
    const int cj = (tid & 15) * 4, ri = tid >> 4;
#pragma unroll
    for (int k = 0; k < 4; k++) {
        int r = ri + k * 16;
        *(ushort4*)&tls[r][cj] = *(const ushort4*)&in[(size_t)(by + r) * 3072 + bx + cj];
    }
    __syncthreads();
#pragma unroll
    for (int k = 0; k < 4; k++) {
        int i2 = ri + k * 16;
        ushort4 o;
        o.x = __builtin_bit_cast(u16, tls[cj + 0][i2]);
        o.y = __builtin_bit_cast(u16, tls[cj + 1][i2]);
        o.z = __builtin_bit_cast(u16, tls[cj + 2][i2]);
        o.w = __builtin_bit_cast(u16, tls[cj + 3][i2]);
        *(ushort4*)&out[(size_t)(bx + i2) * 1024 + by + cj] = o;
    }
}

// ---------------------------------------------------------------------------
// residual + LayerNorm: t = xin + add; y = LN(t)*g + beta
// ---------------------------------------------------------------------------
__global__ __launch_bounds__(256)
void ln_kernel(const float* __restrict__ xin, const bf16_t* __restrict__ add,
               const float* __restrict__ g, const float* __restrict__ beta,
               float* __restrict__ xout, bf16_t* __restrict__ bout)
{
    __shared__ float red[8];
    const int row = blockIdx.x;
    const int t = threadIdx.x;
    const size_t base = (size_t)row * 1024 + t * 4;
    float4 xv = *(const float4*)&xin[base];
    ushort4 au = *(const ushort4*)&add[base];
    float tv[4];
    tv[0] = xv.x + bf2f(au.x);
    tv[1] = xv.y + bf2f(au.y);
    tv[2] = xv.z + bf2f(au.z);
    tv[3] = xv.w + bf2f(au.w);
    float s = tv[0] + tv[1] + tv[2] + tv[3];
    float s2 = tv[0] * tv[0] + tv[1] * tv[1] + tv[2] * tv[2] + tv[3] * tv[3];
#pragma unroll
    for (int o = 32; o; o >>= 1) { s += __shfl_xor(s, o, 64); s2 += __shfl_xor(s2, o, 64); }
    if ((t & 63) == 0) { red[t >> 6] = s; red[4 + (t >> 6)] = s2; }
    __syncthreads();
    s = red[0] + red[1] + red[2] + red[3];
    s2 = red[4] + red[5] + red[6] + red[7];
    const float mu = s * (1.f / 1024.f);
    const float var = s2 * (1.f / 1024.f) - mu * mu;
    const float rs = rsqrtf(var + 1e-5f);
    float4 gu = *(const float4*)&g[t * 4];
    float4 bu = *(const float4*)&beta[t * 4];
    float y0 = (tv[0] - mu) * rs * gu.x + bu.x;
    float y1 = (tv[1] - mu) * rs * gu.y + bu.y;
    float y2 = (tv[2] - mu) * rs * gu.z + bu.z;
    float y3 = (tv[3] - mu) * rs * gu.w + bu.w;
    float4 yo = {y0, y1, y2, y3};
    *(float4*)&xout[base] = yo;
    ushort4 ob = {f2bf(y0), f2bf(y1), f2bf(y2), f2bf(y3)};
    *(ushort4*)&bout[base] = ob;
}

// ---------------------------------------------------------------------------
// residual + 4-plane-sum + bias + LayerNorm (for split-K FF2)
// ---------------------------------------------------------------------------
__global__ __launch_bounds__(256)
void ln4_kernel(const float* __restrict__ xin, const bf16_t* __restrict__ p,
                long pstride, const float* __restrict__ fbias,
                const float* __restrict__ g, const float* __restrict__ beta,
                float* __restrict__ xout, bf16_t* __restrict__ bout)
{
    __shared__ float red[8];
    const int row = blockIdx.x;
    const int t = threadIdx.x;
    const size_t base = (size_t)row * 1024 + t * 4;
    float4 xv = *(const float4*)&xin[base];
    float4 bb = *(const float4*)&fbias[t * 4];
    float tv[4] = {xv.x + bb.x, xv.y + bb.y, xv.z + bb.z, xv.w + bb.w};
#pragma unroll
    for (int z = 0; z < 4; z++) {
        ushort4 au = *(const ushort4*)&p[(size_t)z * pstride + base];
        tv[0] += bf2f(au.x); tv[1] += bf2f(au.y);
        tv[2] += bf2f(au.z); tv[3] += bf2f(au.w);
    }
    float s = tv[0] + tv[1] + tv[2] + tv[3];
    float s2 = tv[0] * tv[0] + tv[1] * tv[1] + tv[2] * tv[2] + tv[3] * tv[3];
#pragma unroll
    for (int o = 32; o; o >>= 1) { s += __shfl_xor(s, o, 64); s2 += __shfl_xor(s2, o, 64); }
    if ((t & 63) == 0) { red[t >> 6] = s; red[4 + (t >> 6)] = s2; }
    __syncthreads();
    s = red[0] + red[1] + red[2] + red[3];
    s2 = red[4] + red[5] + red[6] + red[7];
    const float mu = s * (1.f / 1024.f);
    const float var = s2 * (1.f / 1024.f) - mu * mu;
    const float rs = rsqrtf(var + 1e-5f);
    float4 gu = *(const float4*)&g[t * 4];
    float4 bu = *(const float4*)&beta[t * 4];
    float y0 = (tv[0] - mu) * rs * gu.x + bu.x;
    float y1 = (tv[1] - mu) * rs * gu.y + bu.y;
    float y2 = (tv[2] - mu) * rs * gu.z + bu.z;
    float y3 = (tv[3] - mu) * rs * gu.w + bu.w;
    float4 yo = {y0, y1, y2, y3};
    *(float4*)&xout[base] = yo;
    ushort4 ob = {f2bf(y0), f2bf(y1), f2bf(y2), f2bf(y3)};
    *(ushort4*)&bout[base] = ob;
}

// ---------------------------------------------------------------------------

extern "C" void kernel_launch(void* const* d_in, const int* in_sizes, int n_in,
                              void* d_out, int out_size, void* d_ws, size_t ws_size,
                              hipStream_t stream)
{
    const int*   ids = (const int*)d_in[0];
    const int*   am  = (const int*)d_in[1];
    const float* emb = (const float*)d_in[2];
    const float* Wq  = (const float*)d_in[3];
    const float* Wk  = (const float*)d_in[4];
    const float* Wv  = (const float*)d_in[5];
    const float* bq  = (const float*)d_in[6];
    const float* bk  = (const float*)d_in[7];
    const float* bv  = (const float*)d_in[8];
    const float* g1  = (const float*)d_in[9];
    const float* be1 = (const float*)d_in[10];
    const float* Wf1 = (const float*)d_in[11];
    const float* bf1 = (const float*)d_in[12];
    const float* Wf2 = (const float*)d_in[13];
    const float* bf2_ = (const float*)d_in[14];
    const float* g2  = (const float*)d_in[15];
    const float* be2 = (const float*)d_in[16];

    char* ws = (char*)d_ws;
    float*  x      = (float*)(ws);                      // 16 MB  [0,16)
    bf16_t* xb     = (bf16_t*)(ws + (16LL << 20));      // 8 MB   [16,24)
    bf16_t* qkv    = (bf16_t*)(ws + (24LL << 20));      // 24 MB  [24,48)
    bf16_t* vt     = (bf16_t*)(ws + (48LL << 20));      // 8 MB   [48,56)
    bf16_t* fpart  = (bf16_t*)(ws + (24LL << 20));      // 32 MB  [24,56) (aliases qkv/vt)
    float*  scores = (float*)(ws + (56LL << 20));       // 16 MB  [56,72) (aliases h)
    bf16_t* p      = (bf16_t*)(ws + (72LL << 20));      // 8 MB   [72,80) (aliases h)
    bf16_t* h      = (bf16_t*)(ws + (56LL << 20));      // 32 MB  [56,88)
    bf16_t* attn   = (bf16_t*)(ws + (88LL << 20));      // 8 MB   [88,96)
    bf16_t* wqkvTA = (bf16_t*)(ws + (96LL << 20));      // 36 MB  [96,132)
    bf16_t* wf1TA  = (bf16_t*)(ws + (132LL << 20));     // 48 MB  [132,180)
    bf16_t* wf2TA  = (bf16_t*)(ws + (180LL << 20));     // 48 MB  [180,228)
    float*  qbiasA = (float*)(ws + (228LL << 20));      // 72 KB

    const size_t DD = 1024 * 1024;

    prep_kernel<<<21064, 256, 0, stream>>>(Wq, Wk, Wv, Wf1, Wf2, bq, bk, bv,
                                           ids, emb, wqkvTA, wf1TA, wf2TA, qbiasA, x, xb);

    for (int l = 0; l < 6; l++) {
        // fused QKV: [4096,1024] x [3072,1024]^T -> qkv [4096,3072]
        gemm8p<0><<<dim3(12, 16, 1), 512, 0, stream>>>(xb, 1024, wqkvTA + (size_t)l * 3 * DD, 1024,
                                                       qkv, 3072, qbiasA + l * 3072, 1024, 0, 0);
        // scores = Q K^T * 1/32  (f32)
        gemm_db<2><<<dim3(8, 8, 4), 256, 0, stream>>>(qkv, 3072, 1024L * 3072,
                                                      qkv + 1024, 3072, 1024L * 3072,
                                                      scores, 1024, 1024L * 1024,
                                                      nullptr, 1024, 0.03125f);
        // softmax + V^T (merged)
        softvt_kernel<<<2048, 256, 0, stream>>>(scores, am, p, qkv, vt);
        // attn = P V  (via V^T as Bt)
        gemm_db<0><<<dim3(8, 8, 4), 256, 0, stream>>>(p, 1024, 1024L * 1024,
                                                      vt, 1024, 1024L * 1024,
                                                      attn, 1024, 1024L * 1024,
                                                      nullptr, 1024, 0.f);
        ln_kernel<<<4096, 256, 0, stream>>>(x, attn, g1 + l * 1024, be1 + l * 1024, x, xb);
        // FF1 with relu -> h [4096,4096]
        gemm8p<1><<<dim3(16, 16, 1), 512, 0, stream>>>(xb, 1024, wf1TA + (size_t)l * 4 * DD, 1024,
                                                       h, 4096, bf1 + l * 4096, 1024, 0, 0);
        // FF2 split-K=4 -> fpart
        gemm8p<0><<<dim3(4, 16, 4), 512, 0, stream>>>(h, 4096, wf2TA + (size_t)l * 4 * DD, 4096,
                                                      fpart, 1024, nullptr, 1024,
                                                      1024, 4096L * 1024);
        float* xo = (l == 5) ? (float*)d_out : x;
        ln4_kernel<<<4096, 256, 0, stream>>>(x, fpart, 4096L * 1024, bf2_ + l * 1024,
                                             g2 + l * 1024, be2 + l * 1024, xo, xb);
    }
    (void)in_sizes; (void)n_in; (void)out_size; (void)ws_size;
}

// Round 8
// 1262.401 us; speedup vs baseline: 1.2653x; 1.0091x over previous
//
#include <hip/hip_runtime.h>

typedef __bf16 bf16_t;
typedef __bf16 bf16x8 __attribute__((ext_vector_type(8)));
typedef float f32x4 __attribute__((ext_vector_type(4)));
typedef unsigned short u16;

#define DEV static __device__ __forceinline__

DEV float bf2f(u16 u) { __bf16 h = __builtin_bit_cast(__bf16, u); return (float)h; }
DEV u16 f2bf(float f) { __bf16 h = (__bf16)f; return __builtin_bit_cast(u16, h); }

// async global->LDS, 16B per lane; lds base must be wave-uniform.
DEV void gll16(bf16_t* lds, const bf16_t* g) {
    __builtin_amdgcn_global_load_lds(
        (const __attribute__((address_space(1))) void*)g,
        (__attribute__((address_space(3))) void*)lds, 16, 0, 0);
}

#define WAITV(N) asm volatile("s_waitcnt vmcnt(" #N ")" ::: "memory")

// ---------------------------------------------------------------------------
// 256x256-tile GEMM, 8 waves (2M x 4N), BK=64, double-buffered 128KiB LDS.
// Two barriers per K-tile; counted vmcnt (never 0 in steady state).
// EPI: 0 = bf16 out (+f32 bias if non-null), 1 = bf16 out + bias + relu
// ---------------------------------------------------------------------------
template <int EPI>
__global__ __launch_bounds__(512, 1)
void gemm8p(const bf16_t* __restrict__ A, int lda,
            const bf16_t* __restrict__ Bt, int ldb,
            bf16_t* __restrict__ C, int ldc,
            const float* __restrict__ bias, int K,
            long kadv, long cadv)
{
    __shared__ bf16_t Asm[2 * 2 * 8192];   // [buf][half][128*64]
    __shared__ bf16_t Bsm[2 * 2 * 8192];
    const int tid = threadIdx.x, w = tid >> 6, l = tid & 63;
    const int z = blockIdx.z;
    A  += (size_t)z * kadv;
    Bt += (size_t)z * kadv;
    C  += (size_t)z * cadv;

    const int gx = gridDim.x;
    int lin = blockIdx.y * gx + blockIdx.x;
    const int nlin = gx * gridDim.y;
    lin = (lin & 7) * (nlin >> 3) + (lin >> 3);
    const size_t row0 = (size_t)(lin / gx) * 256;
    const size_t col0 = (size_t)(lin % gx) * 256;

    const int wr = w >> 2, wc = w & 3;
    const int bh = wc >> 1;
    const int browoff = (wc & 1) * 64;
    const int fr = l & 15, q = l >> 4, sw = l & 7;

    const int srow = w * 8 + (l >> 3);
    const int sslot8 = ((l & 7) ^ ((l >> 3) & 7)) * 8;
    const bf16_t* AgH0 = A  + (row0 + srow) * (size_t)lda + sslot8;
    const bf16_t* BgH0 = Bt + (col0 + srow) * (size_t)ldb + sslot8;
    const size_t a128 = (size_t)128 * lda, b128 = (size_t)128 * ldb;
    const size_t a64  = (size_t)64 * lda,  b64  = (size_t)64 * ldb;
    const int wlds = w * 512;

#define STAGE_PAIR(buf, tt, p)                                                 \
    do {                                                                       \
        const int koff = (tt) * 64;                                            \
        if ((p) == 0) {                                                        \
            gll16(Asm + ((buf)*2+0)*8192 + wlds,        AgH0 + koff);          \
            gll16(Asm + ((buf)*2+0)*8192 + 4096 + wlds, AgH0 + koff + a64);    \
        } else if ((p) == 1) {                                                 \
            gll16(Asm + ((buf)*2+1)*8192 + wlds,        AgH0 + a128 + koff);   \
            gll16(Asm + ((buf)*2+1)*8192 + 4096 + wlds, AgH0 + a128 + koff + a64); \
        } else if ((p) == 2) {                                                 \
            gll16(Bsm + ((buf)*2+0)*8192 + wlds,        BgH0 + koff);          \
            gll16(Bsm + ((buf)*2+0)*8192 + 4096 + wlds, BgH0 + koff + b64);    \
        } else {                                                               \
            gll16(Bsm + ((buf)*2+1)*8192 + wlds,        BgH0 + b128 + koff);   \
            gll16(Bsm + ((buf)*2+1)*8192 + 4096 + wlds, BgH0 + b128 + koff + b64); \
        }                                                                      \
    } while (0)

    f32x4 acc[8][4] = {};
    const int NT = K >> 6;

    STAGE_PAIR(0, 0, 0); STAGE_PAIR(0, 0, 1); STAGE_PAIR(0, 0, 2); STAGE_PAIR(0, 0, 3);
    if (NT > 1) { STAGE_PAIR(1, 1, 0); WAITV(2); } else { WAITV(0); }
    __builtin_amdgcn_sched_barrier(0);
    __builtin_amdgcn_s_barrier();

    for (int t = 0; t < NT; ++t) {
        const int cur = t & 1, nxt = cur ^ 1;
        const bool hasN1 = (t + 1 < NT), hasN2 = (t + 2 < NT);
        const bf16_t* Ab = Asm + (cur * 2 + wr) * 8192;
        const bf16_t* Bb = Bsm + (cur * 2 + bh) * 8192;

        // region 1: read A(mi0-3) + B(all); stage t+1 pairs 1,2; 32 MFMA
        bf16x8 aR[4][2], bR[4][2];
#pragma unroll
        for (int mi = 0; mi < 4; mi++)
#pragma unroll
            for (int kk = 0; kk < 2; kk++)
                aR[mi][kk] = *(const bf16x8*)&Ab[(mi * 16 + fr) * 64 + ((kk * 4 + q) ^ sw) * 8];
#pragma unroll
        for (int ni = 0; ni < 4; ni++)
#pragma unroll
            for (int kk = 0; kk < 2; kk++)
                bR[ni][kk] = *(const bf16x8*)&Bb[(browoff + ni * 16 + fr) * 64 + ((kk * 4 + q) ^ sw) * 8];
        if (hasN1) { STAGE_PAIR(nxt, t + 1, 1); STAGE_PAIR(nxt, t + 1, 2); }
        __builtin_amdgcn_s_setprio(1);
#pragma unroll
        for (int mi = 0; mi < 4; mi++)
#pragma unroll
            for (int ni = 0; ni < 4; ni++)
#pragma unroll
                for (int kk = 0; kk < 2; kk++)
                    acc[mi][ni] = __builtin_amdgcn_mfma_f32_16x16x32_bf16(aR[mi][kk], bR[ni][kk], acc[mi][ni], 0, 0, 0);
        __builtin_amdgcn_s_setprio(0);

        // region 2: read A(mi4-7); stage t+1 pair 3; 32 MFMA
        bf16x8 a2[4][2];
#pragma unroll
        for (int mi = 0; mi < 4; mi++)
#pragma unroll
            for (int kk = 0; kk < 2; kk++)
                a2[mi][kk] = *(const bf16x8*)&Ab[((4 + mi) * 16 + fr) * 64 + ((kk * 4 + q) ^ sw) * 8];
        if (hasN1) STAGE_PAIR(nxt, t + 1, 3);
        __builtin_amdgcn_s_setprio(1);
#pragma unroll
        for (int mi = 0; mi < 4; mi++)
#pragma unroll
            for (int ni = 0; ni < 4; ni++)
#pragma unroll
                for (int kk = 0; kk < 2; kk++)
                    acc[4 + mi][ni] = __builtin_amdgcn_mfma_f32_16x16x32_bf16(a2[mi][kk], bR[ni][kk], acc[4 + mi][ni], 0, 0, 0);
        __builtin_amdgcn_s_setprio(0);

        __builtin_amdgcn_s_barrier();      // all reads of cur drained
        if (hasN2) STAGE_PAIR(cur, t + 2, 0);
        if (hasN1) {
            if (hasN2) { WAITV(2); } else { WAITV(0); }
            __builtin_amdgcn_sched_barrier(0);
        }
        __builtin_amdgcn_s_barrier();      // t+1 buffer published
    }
#undef STAGE_PAIR

    const int cr = q * 4, cc = fr;
#pragma unroll
    for (int ni = 0; ni < 4; ni++) {
        size_t c = col0 + wc * 64 + ni * 16 + cc;
        float bv = bias ? bias[c] : 0.f;
#pragma unroll
        for (int mi = 0; mi < 8; mi++) {
            size_t r = row0 + wr * 128 + mi * 16 + cr;
#pragma unroll
            for (int j = 0; j < 4; j++) {
                float v = acc[mi][ni][j] + bv;
                if (EPI == 1) v = fmaxf(v, 0.f);
                C[(r + j) * ldc + c] = (bf16_t)v;
            }
        }
    }
}

// ---------------------------------------------------------------------------
// 128x128-tile GEMM, 4 waves, BK=64, double-buffered LDS (64 KiB), 2 barriers
// per K-tile, counted vmcnt(4).
// EPI: 0 bf16+bias, 1 +relu, 2 f32*scale, 3 bf16*scale
// ---------------------------------------------------------------------------
template <int EPI>
__global__ __launch_bounds__(256)
void gemm_db(const bf16_t* __restrict__ A, int lda, long sA,
             const bf16_t* __restrict__ Bt, int ldb, long sB,
             void* __restrict__ Cv, int ldc, long sC,
             const float* __restrict__ bias, int K, float scale)
{
    __shared__ bf16_t Asm[2][128 * 64];
    __shared__ bf16_t Bsm[2][128 * 64];
    const int tid = threadIdx.x, w = tid >> 6, l = tid & 63;
    const int bz = blockIdx.z;

    const int gx = gridDim.x;
    int lin = blockIdx.y * gx + blockIdx.x;
    const int nlin = gx * gridDim.y;
    lin = (lin & 7) * (nlin >> 3) + (lin >> 3);
    const size_t row0 = (size_t)(lin / gx) * 128;
    const size_t col0 = (size_t)(lin % gx) * 128;

    A  += (size_t)bz * sA;
    Bt += (size_t)bz * sB;

    const int lr = l >> 3;
    const int sl = (l & 7) ^ lr;
    const bf16_t* Ag = A  + (row0 + (size_t)(w * 32) + lr) * lda + sl * 8;
    const bf16_t* Bg = Bt + (col0 + (size_t)(w * 32) + lr) * ldb + sl * 8;
    const int wlds = (w * 32) * 64;

#define STA(buf, tt)                                                           \
    do { const int ko = (tt) * 64;                                             \
        _Pragma("unroll")                                                      \
        for (int c = 0; c < 4; c++)                                            \
            gll16(&Asm[buf][wlds + c * 8 * 64], Ag + (size_t)(c * 8) * lda + ko); \
    } while (0)
#define STB(buf, tt)                                                           \
    do { const int ko = (tt) * 64;                                             \
        _Pragma("unroll")                                                      \
        for (int c = 0; c < 4; c++)                                            \
            gll16(&Bsm[buf][wlds + c * 8 * 64], Bg + (size_t)(c * 8) * ldb + ko); \
    } while (0)

    const int wm = (w >> 1) * 64, wn = (w & 1) * 64;
    const int fr16 = l & 15, q4 = l >> 4, sw = l & 7;
    f32x4 acc[4][4] = {};
    const int NT = K >> 6;

    STA(0, 0); STB(0, 0);
    if (NT > 1) { STA(1, 1); WAITV(4); } else { WAITV(0); }
    __builtin_amdgcn_sched_barrier(0);
    __builtin_amdgcn_s_barrier();

    for (int t = 0; t < NT; ++t) {
        const int cur = t & 1, nxt = cur ^ 1;
        const bool hasN1 = (t + 1 < NT), hasN2 = (t + 2 < NT);

        bf16x8 a0[4], b0[4], a1[4], b1[4];
        const int s0 = (q4 ^ sw) * 8, s1 = ((4 + q4) ^ sw) * 8;
#pragma unroll
        for (int i = 0; i < 4; i++) {
            a0[i] = *(const bf16x8*)&Asm[cur][(wm + i * 16 + fr16) * 64 + s0];
            b0[i] = *(const bf16x8*)&Bsm[cur][(wn + i * 16 + fr16) * 64 + s0];
        }
        if (hasN1) STB(nxt, t + 1);
        __builtin_amdgcn_s_setprio(1);
#pragma unroll
        for (int mi = 0; mi < 4; mi++)
#pragma unroll
            for (int ni = 0; ni < 4; ni++)
                acc[mi][ni] = __builtin_amdgcn_mfma_f32_16x16x32_bf16(a0[mi], b0[ni], acc[mi][ni], 0, 0, 0);
        __builtin_amdgcn_s_setprio(0);
#pragma unroll
        for (int i = 0; i < 4; i++) {
            a1[i] = *(const bf16x8*)&Asm[cur][(wm + i * 16 + fr16) * 64 + s1];
            b1[i] = *(const bf16x8*)&Bsm[cur][(wn + i * 16 + fr16) * 64 + s1];
        }
        __builtin_amdgcn_s_setprio(1);
#pragma unroll
        for (int mi = 0; mi < 4; mi++)
#pragma unroll
            for (int ni = 0; ni < 4; ni++)
                acc[mi][ni] = __builtin_amdgcn_mfma_f32_16x16x32_bf16(a1[mi], b1[ni], acc[mi][ni], 0, 0, 0);
        __builtin_amdgcn_s_setprio(0);

        __builtin_amdgcn_s_barrier();
        if (hasN2) STA(cur, t + 2);
        if (hasN1) {
            if (hasN2) { WAITV(4); } else { WAITV(0); }
            __builtin_amdgcn_sched_barrier(0);
        }
        __builtin_amdgcn_s_barrier();
    }
#undef STA
#undef STB

    const int cr = q4 * 4, cc = fr16;
    if (EPI == 2) {
        float* C = (float*)Cv + (size_t)bz * sC;
#pragma unroll
        for (int mi = 0; mi < 4; mi++)
#pragma unroll
            for (int ni = 0; ni < 4; ni++) {
                size_t r = row0 + wm + mi * 16 + cr;
                size_t c = col0 + wn + ni * 16 + cc;
#pragma unroll
                for (int j = 0; j < 4; j++)
                    C[(r + j) * ldc + c] = acc[mi][ni][j] * scale;
            }
    } else if (EPI == 3) {
        bf16_t* C = (bf16_t*)Cv + (size_t)bz * sC;
#pragma unroll
        for (int mi = 0; mi < 4; mi++)
#pragma unroll
            for (int ni = 0; ni < 4; ni++) {
                size_t r = row0 + wm + mi * 16 + cr;
                size_t c = col0 + wn + ni * 16 + cc;
#pragma unroll
                for (int j = 0; j < 4; j++)
                    C[(r + j) * ldc + c] = (bf16_t)(acc[mi][ni][j] * scale);
            }
    } else {
        bf16_t* C = (bf16_t*)Cv + (size_t)bz * sC;
#pragma unroll
        for (int ni = 0; ni < 4; ni++) {
            size_t c = col0 + wn + ni * 16 + cc;
            float bv = bias ? bias[c] : 0.f;
#pragma unroll
            for (int mi = 0; mi < 4; mi++) {
                size_t r = row0 + wm + mi * 16 + cr;
#pragma unroll
                for (int j = 0; j < 4; j++) {
                    float v = acc[mi][ni][j] + bv;
                    if (EPI == 1) v = fmaxf(v, 0.f);
                    C[(r + j) * ldc + c] = (bf16_t)v;
                }
            }
        }
    }
}

// ---------------------------------------------------------------------------
// one-shot preprocessing: weight convert-transposes + bias concat + embed.
// Transpose tile uses 4-col-group XOR swizzle keyed on (r>>2)&15 -> read phase
// hits 16 distinct banks per quarter-wave (was 8-way conflict with padding).
// ---------------------------------------------------------------------------
__global__ __launch_bounds__(256)
void prep_kernel(const float* __restrict__ Wq, const float* __restrict__ Wk,
                 const float* __restrict__ Wv, const float* __restrict__ Wf1,
                 const float* __restrict__ Wf2,
                 const float* __restrict__ bq, const float* __restrict__ bk,
                 const float* __restrict__ bv,
                 const int* __restrict__ ids, const float* __restrict__ emb,
                 bf16_t* __restrict__ wqkvTA, bf16_t* __restrict__ wf1TA,
                 bf16_t* __restrict__ wf2TA, float* __restrict__ qbiasA,
                 float* __restrict__ x, bf16_t* __restrict__ xb)
{
    __shared__ bf16_t tls[64 * 64];
    const size_t DD = 1024 * 1024;
    int id = blockIdx.x;
    if (id < 16896) {
        const float* src; bf16_t* dst; int ldin, ldout, bx, by;
        if (id < 4608) {
            int layer = id / 768, r = id % 768, which = r >> 8, t = r & 255;
            src = (which == 0 ? Wq : which == 1 ? Wk : Wv) + (size_t)layer * DD;
            dst = wqkvTA + (size_t)layer * 3 * DD + (size_t)which * DD;
            ldin = 1024; ldout = 1024; bx = (t & 15) * 64; by = (t >> 4) * 64;
        } else if (id < 10752) {
            int i = id - 4608, layer = i >> 10, t = i & 1023;
            src = Wf1 + (size_t)layer * 4 * DD; dst = wf1TA + (size_t)layer * 4 * DD;
            ldin = 4096; ldout = 1024; bx = (t & 63) * 64; by = (t >> 6) * 64;
        } else {
            int i = id - 10752, layer = i >> 10, t = i & 1023;
            src = Wf2 + (size_t)layer * 4 * DD; dst = wf2TA + (size_t)layer * 4 * DD;
            ldin = 1024; ldout = 4096; bx = (t & 15) * 64; by = (t >> 4) * 64;
        }
        const int tid = threadIdx.x;
        const int cg = tid & 15, ri = tid >> 4;   // col-group (c>>2), row base
#pragma unroll
        for (int k = 0; k < 4; k++) {
            int r = ri + k * 16;
            float4 v = *(const float4*)&src[(size_t)(by + r) * ldin + bx + cg * 4];
            ushort4 o = {f2bf(v.x), f2bf(v.y), f2bf(v.z), f2bf(v.w)};
            int g = cg ^ ((r >> 2) & 15);          // swizzled group
            *(ushort4*)&tls[r * 64 + g * 4] = o;
        }
        __syncthreads();
#pragma unroll
        for (int k = 0; k < 4; k++) {
            int i2 = ri + k * 16;                  // source column / out row
            int gr = (i2 >> 2) ^ cg;               // group holding col i2 in rows cg*4..
            ushort4 o;
            o.x = __builtin_bit_cast(u16, tls[(cg * 4 + 0) * 64 + gr * 4 + (i2 & 3)]);
            o.y = __builtin_bit_cast(u16, tls[(cg * 4 + 1) * 64 + gr * 4 + (i2 & 3)]);
            o.z = __builtin_bit_cast(u16, tls[(cg * 4 + 2) * 64 + gr * 4 + (i2 & 3)]);
            o.w = __builtin_bit_cast(u16, tls[(cg * 4 + 3) * 64 + gr * 4 + (i2 & 3)]);
            *(ushort4*)&dst[(size_t)(bx + i2) * ldout + by + cg * 4] = o;
        }
        return;
    }
    id -= 16896;
    if (id < 72) {
        int i = id * 256 + threadIdx.x;
        int lyr = i / 3072, j = i - lyr * 3072;
        qbiasA[i] = (j < 1024) ? bq[lyr * 1024 + j]
                  : (j < 2048) ? bk[lyr * 1024 + j - 1024]
                               : bv[lyr * 1024 + j - 2048];
        return;
    }
    id -= 72;
    const int row = id;
    const int s = row & 1023;
    const int eid = ids[row];
    const float* er = emb + (size_t)eid * 1024;
    float* xr = x + (size_t)row * 1024;
    bf16_t* br = xb + (size_t)row * 1024;
#pragma unroll
    for (int k = 0; k < 2; k++) {
        int i = threadIdx.x + 256 * k;
        int d = 2 * i;
        float dv = expf((float)d * -0.008994473019508f);
        float ph = (float)s * dv;
        float sv, cv;
        sincosf(ph, &sv, &cv);
        float2 ev = *(const float2*)&er[d];
        float x0 = ev.x + sv;
        float x1 = ev.y + cv;
        float2 xo = {x0, x1};
        *(float2*)&xr[d] = xo;
        ushort2 bo = {f2bf(x0), f2bf(x1)};
        *(ushort2*)&br[d] = bo;
    }
}

// ---------------------------------------------------------------------------
// merged masked-softmax over bf16 scores (blocks 0..1023) + V^T transpose
// (blocks 1024..2047).
// ---------------------------------------------------------------------------
__global__ __launch_bounds__(256)
void softvt_kernel(const bf16_t* __restrict__ sc, const int* __restrict__ amask,
                   bf16_t* __restrict__ p, const bf16_t* __restrict__ qkv,
                   bf16_t* __restrict__ vt)
{
    __shared__ bf16_t tls[64][72];
    int bid = blockIdx.x;
    if (bid < 1024) {
        const int row = bid * 4 + (threadIdx.x >> 6);
        const int l = threadIdx.x & 63;
        const int b = row >> 10;
        const bf16_t* s = sc + (size_t)row * 1024;
        const int* m = amask + (size_t)b * 1024;
        float v[16];
        float mx = -3.0e38f;
#pragma unroll
        for (int i = 0; i < 4; i++) {
            int c = 4 * l + 256 * i;
            ushort4 su = *(const ushort4*)&s[c];
            int4 mv = *(const int4*)&m[c];
            v[4 * i + 0] = mv.x ? bf2f(su.x) : -1e9f;
            v[4 * i + 1] = mv.y ? bf2f(su.y) : -1e9f;
            v[4 * i + 2] = mv.z ? bf2f(su.z) : -1e9f;
            v[4 * i + 3] = mv.w ? bf2f(su.w) : -1e9f;
            mx = fmaxf(mx, fmaxf(fmaxf(v[4 * i], v[4 * i + 1]), fmaxf(v[4 * i + 2], v[4 * i + 3])));
        }
#pragma unroll
        for (int o = 32; o; o >>= 1) mx = fmaxf(mx, __shfl_xor(mx, o, 64));
        float sum = 0.f;
#pragma unroll
        for (int i = 0; i < 16; i++) { v[i] = __expf(v[i] - mx); sum += v[i]; }
#pragma unroll
        for (int o = 32; o; o >>= 1) sum += __shfl_xor(sum, o, 64);
        float inv = 1.0f / sum;
#pragma unroll
        for (int i = 0; i < 4; i++) {
            int c = 4 * l + 256 * i;
            ushort4 st;
            st.x = f2bf(v[4 * i + 0] * inv);
            st.y = f2bf(v[4 * i + 1] * inv);
            st.z = f2bf(v[4 * i + 2] * inv);
            st.w = f2bf(v[4 * i + 3] * inv);
            *(ushort4*)&p[(size_t)row * 1024 + c] = st;
        }
        return;
    }
    bid -= 1024;
    const int z = bid >> 8, t = bid & 255;
    const bf16_t* in = qkv + 2048 + (size_t)z * 1024 * 3072;
    bf16_t* out = vt + (size_t)z * 1024 * 1024;
    const int bx = (t & 15) * 64, by = (t >> 4) * 64;
    const int tid = threadIdx.x;
    const int cj = (tid & 15) * 4, ri = tid >> 4;
#pragma unroll
    for (int k = 0; k < 4; k++) {
        int r = ri + k * 16;
        *(ushort4*)&tls[r][cj] = *(const ushort4*)&in[(size_t)(by + r) * 3072 + bx + cj];
    }
    __syncthreads();
#pragma unroll
    for (int k = 0; k < 4; k++) {
        int i2 = ri + k * 16;
        ushort4 o;
        o.x = __builtin_bit_cast(u16, tls[cj + 0][i2]);
        o.y = __builtin_bit_cast(u16, tls[cj + 1][i2]);
        o.z = __builtin_bit_cast(u16, tls[cj + 2][i2]);
        o.w = __builtin_bit_cast(u16, tls[cj + 3][i2]);
        *(ushort4*)&out[(size_t)(bx + i2) * 1024 + by + cj] = o;
    }
}

// ---------------------------------------------------------------------------
// residual + LayerNorm: t = xin + add; y = LN(t)*g + beta
// ---------------------------------------------------------------------------
__global__ __launch_bounds__(256)
void ln_kernel(const float* __restrict__ xin, const bf16_t* __restrict__ add,
               const float* __restrict__ g, const float* __restrict__ beta,
               float* __restrict__ xout, bf16_t* __restrict__ bout)
{
    __shared__ float red[8];
    const int row = blockIdx.x;
    const int t = threadIdx.x;
    const size_t base = (size_t)row * 1024 + t * 4;
    float4 xv = *(const float4*)&xin[base];
    ushort4 au = *(const ushort4*)&add[base];
    float tv[4];
    tv[0] = xv.x + bf2f(au.x);
    tv[1] = xv.y + bf2f(au.y);
    tv[2] = xv.z + bf2f(au.z);
    tv[3] = xv.w + bf2f(au.w);
    float s = tv[0] + tv[1] + tv[2] + tv[3];
    float s2 = tv[0] * tv[0] + tv[1] * tv[1] + tv[2] * tv[2] + tv[3] * tv[3];
#pragma unroll
    for (int o = 32; o; o >>= 1) { s += __shfl_xor(s, o, 64); s2 += __shfl_xor(s2, o, 64); }
    if ((t & 63) == 0) { red[t >> 6] = s; red[4 + (t >> 6)] = s2; }
    __syncthreads();
    s = red[0] + red[1] + red[2] + red[3];
    s2 = red[4] + red[5] + red[6] + red[7];
    const float mu = s * (1.f / 1024.f);
    const float var = s2 * (1.f / 1024.f) - mu * mu;
    const float rs = rsqrtf(var + 1e-5f);
    float4 gu = *(const float4*)&g[t * 4];
    float4 bu = *(const float4*)&beta[t * 4];
    float y0 = (tv[0] - mu) * rs * gu.x + bu.x;
    float y1 = (tv[1] - mu) * rs * gu.y + bu.y;
    float y2 = (tv[2] - mu) * rs * gu.z + bu.z;
    float y3 = (tv[3] - mu) * rs * gu.w + bu.w;
    float4 yo = {y0, y1, y2, y3};
    *(float4*)&xout[base] = yo;
    ushort4 ob = {f2bf(y0), f2bf(y1), f2bf(y2), f2bf(y3)};
    *(ushort4*)&bout[base] = ob;
}

// ---------------------------------------------------------------------------
// residual + 4-plane-sum + bias + LayerNorm (for split-K FF2)
// ---------------------------------------------------------------------------
__global__ __launch_bounds__(256)
void ln4_kernel(const float* __restrict__ xin, const bf16_t* __restrict__ p,
                long pstride, const float* __restrict__ fbias,
                const float* __restrict__ g, const float* __restrict__ beta,
                float* __restrict__ xout, bf16_t* __restrict__ bout)
{
    __shared__ float red[8];
    const int row = blockIdx.x;
    const int t = threadIdx.x;
    const size_t base = (size_t)row * 1024 + t * 4;
    float4 xv = *(const float4*)&xin[base];
    float4 bb = *(const float4*)&fbias[t * 4];
    float tv[4] = {xv.x + bb.x, xv.y + bb.y, xv.z + bb.z, xv.w + bb.w};
#pragma unroll
    for (int z = 0; z < 4; z++) {
        ushort4 au = *(const ushort4*)&p[(size_t)z * pstride + base];
        tv[0] += bf2f(au.x); tv[1] += bf2f(au.y);
        tv[2] += bf2f(au.z); tv[3] += bf2f(au.w);
    }
    float s = tv[0] + tv[1] + tv[2] + tv[3];
    float s2 = tv[0] * tv[0] + tv[1] * tv[1] + tv[2] * tv[2] + tv[3] * tv[3];
#pragma unroll
    for (int o = 32; o; o >>= 1) { s += __shfl_xor(s, o, 64); s2 += __shfl_xor(s2, o, 64); }
    if ((t & 63) == 0) { red[t >> 6] = s; red[4 + (t >> 6)] = s2; }
    __syncthreads();
    s = red[0] + red[1] + red[2] + red[3];
    s2 = red[4] + red[5] + red[6] + red[7];
    const float mu = s * (1.f / 1024.f);
    const float var = s2 * (1.f / 1024.f) - mu * mu;
    const float rs = rsqrtf(var + 1e-5f);
    float4 gu = *(const float4*)&g[t * 4];
    float4 bu = *(const float4*)&beta[t * 4];
    float y0 = (tv[0] - mu) * rs * gu.x + bu.x;
    float y1 = (tv[1] - mu) * rs * gu.y + bu.y;
    float y2 = (tv[2] - mu) * rs * gu.z + bu.z;
    float y3 = (tv[3] - mu) * rs * gu.w + bu.w;
    float4 yo = {y0, y1, y2, y3};
    *(float4*)&xout[base] = yo;
    ushort4 ob = {f2bf(y0), f2bf(y1), f2bf(y2), f2bf(y3)};
    *(ushort4*)&bout[base] = ob;
}

// ---------------------------------------------------------------------------

extern "C" void kernel_launch(void* const* d_in, const int* in_sizes, int n_in,
                              void* d_out, int out_size, void* d_ws, size_t ws_size,
                              hipStream_t stream)
{
    const int*   ids = (const int*)d_in[0];
    const int*   am  = (const int*)d_in[1];
    const float* emb = (const float*)d_in[2];
    const float* Wq  = (const float*)d_in[3];
    const float* Wk  = (const float*)d_in[4];
    const float* Wv  = (const float*)d_in[5];
    const float* bq  = (const float*)d_in[6];
    const float* bk  = (const float*)d_in[7];
    const float* bv  = (const float*)d_in[8];
    const float* g1  = (const float*)d_in[9];
    const float* be1 = (const float*)d_in[10];
    const float* Wf1 = (const float*)d_in[11];
    const float* bf1 = (const float*)d_in[12];
    const float* Wf2 = (const float*)d_in[13];
    const float* bf2_ = (const float*)d_in[14];
    const float* g2  = (const float*)d_in[15];
    const float* be2 = (const float*)d_in[16];

    char* ws = (char*)d_ws;
    float*  x      = (float*)(ws);                      // 16 MB  [0,16)
    bf16_t* xb     = (bf16_t*)(ws + (16LL << 20));      // 8 MB   [16,24)
    bf16_t* qkv    = (bf16_t*)(ws + (24LL << 20));      // 24 MB  [24,48)
    bf16_t* vt     = (bf16_t*)(ws + (48LL << 20));      // 8 MB   [48,56)
    bf16_t* fpart  = (bf16_t*)(ws + (24LL << 20));      // 32 MB  [24,56) (aliases qkv/vt)
    bf16_t* scores = (bf16_t*)(ws + (56LL << 20));      // 8 MB   [56,64) (aliases h)
    bf16_t* p      = (bf16_t*)(ws + (72LL << 20));      // 8 MB   [72,80) (aliases h)
    bf16_t* h      = (bf16_t*)(ws + (56LL << 20));      // 32 MB  [56,88)
    bf16_t* attn   = (bf16_t*)(ws + (88LL << 20));      // 8 MB   [88,96)
    bf16_t* wqkvTA = (bf16_t*)(ws + (96LL << 20));      // 36 MB  [96,132)
    bf16_t* wf1TA  = (bf16_t*)(ws + (132LL << 20));     // 48 MB  [132,180)
    bf16_t* wf2TA  = (bf16_t*)(ws + (180LL << 20));     // 48 MB  [180,228)
    float*  qbiasA = (float*)(ws + (228LL << 20));      // 72 KB

    const size_t DD = 1024 * 1024;

    prep_kernel<<<21064, 256, 0, stream>>>(Wq, Wk, Wv, Wf1, Wf2, bq, bk, bv,
                                           ids, emb, wqkvTA, wf1TA, wf2TA, qbiasA, x, xb);

    for (int l = 0; l < 6; l++) {
        // fused QKV: [4096,1024] x [3072,1024]^T -> qkv [4096,3072]
        gemm8p<0><<<dim3(12, 16, 1), 512, 0, stream>>>(xb, 1024, wqkvTA + (size_t)l * 3 * DD, 1024,
                                                       qkv, 3072, qbiasA + l * 3072, 1024, 0, 0);
        // scores = Q K^T * 1/32  (bf16)
        gemm_db<3><<<dim3(8, 8, 4), 256, 0, stream>>>(qkv, 3072, 1024L * 3072,
                                                      qkv + 1024, 3072, 1024L * 3072,
                                                      scores, 1024, 1024L * 1024,
                                                      nullptr, 1024, 0.03125f);
        // softmax + V^T (merged)
        softvt_kernel<<<2048, 256, 0, stream>>>(scores, am, p, qkv, vt);
        // attn = P V  (via V^T as Bt)
        gemm_db<0><<<dim3(8, 8, 4), 256, 0, stream>>>(p, 1024, 1024L * 1024,
                                                      vt, 1024, 1024L * 1024,
                                                      attn, 1024, 1024L * 1024,
                                                      nullptr, 1024, 0.f);
        ln_kernel<<<4096, 256, 0, stream>>>(x, attn, g1 + l * 1024, be1 + l * 1024, x, xb);
        // FF1 with relu -> h [4096,4096]
        gemm8p<1><<<dim3(16, 16, 1), 512, 0, stream>>>(xb, 1024, wf1TA + (size_t)l * 4 * DD, 1024,
                                                       h, 4096, bf1 + l * 4096, 1024, 0, 0);
        // FF2 split-K=4 -> fpart
        gemm8p<0><<<dim3(4, 16, 4), 512, 0, stream>>>(h, 4096, wf2TA + (size_t)l * 4 * DD, 4096,
                                                      fpart, 1024, nullptr, 1024,
                                                      1024, 4096L * 1024);
        float* xo = (l == 5) ? (float*)d_out : x;
        ln4_kernel<<<4096, 256, 0, stream>>>(x, fpart, 4096L * 1024, bf2_ + l * 1024,
                                             g2 + l * 1024, be2 + l * 1024, xo, xb);
    }
    (void)in_sizes; (void)n_in; (void)out_size; (void)ws_size;
}